// Round 8
// baseline (719.992 us; speedup 1.0000x reference)
//
#include <hip/hip_runtime.h>

#define ROWS 6304      // B*N = 32*197
#define MPAD 6400      // 50 * 128
#define CDIM 1024
#define QKVD 3072
#define FFD  4096
#define NSEQ 197
#define NBH  512       // B*H
#define SSZ  38809     // 197*197
#define KPAD 224       // attention K padded to 7*32

typedef __attribute__((ext_vector_type(8))) short bf16x8;
typedef __attribute__((ext_vector_type(4))) float f32x4;
typedef __attribute__((ext_vector_type(4))) int i32x4;

// ---------- device helpers ----------
__device__ __forceinline__ float fqv(float v, float s) {
    float q = rintf(v / s);
    q = fminf(fmaxf(q, -127.0f), 127.0f);
    return q * s;
}
__device__ __forceinline__ float scale_of(const float* am) {
    return fmaxf(am[0] / 127.0f, 1e-8f);
}
__device__ __forceinline__ float gelu_f(float x) {
    const float c = 0.7978845608028654f;  // sqrt(2/pi)
    float t = tanhf(c * (x + 0.044715f * x * x * x));
    return 0.5f * x * (1.0f + t);
}
__device__ __forceinline__ void atomicMaxF(float* p, float v) {
    atomicMax(reinterpret_cast<int*>(p), __float_as_int(v)); // v >= 0 always
}
__device__ __forceinline__ short bf16_of_small_int(float q) {
    return (short)(__float_as_uint(q) >> 16);  // exact for |q| <= 255 integers
}
// block = 256 threads (4 waves) assumed
__device__ __forceinline__ float blockReduceSum(float v, float* sred) {
    int lane = threadIdx.x & 63, w = threadIdx.x >> 6;
    #pragma unroll
    for (int o = 32; o > 0; o >>= 1) v += __shfl_down(v, o);
    __syncthreads();
    if (lane == 0) sred[w] = v;
    __syncthreads();
    return sred[0] + sred[1] + sred[2] + sred[3];
}
__device__ __forceinline__ float blockReduceMax(float v, float* sred) {
    int lane = threadIdx.x & 63, w = threadIdx.x >> 6;
    #pragma unroll
    for (int o = 32; o > 0; o >>= 1) v = fmaxf(v, __shfl_down(v, o));
    __syncthreads();
    if (lane == 0) sred[w] = v;
    __syncthreads();
    return fmaxf(fmaxf(sred[0], sred[1]), fmaxf(sred[2], sred[3]));
}

// ---------- elementwise / reduction kernels ----------
__global__ __launch_bounds__(256) void absmax_kernel(const float* __restrict__ src,
                                                     long long n4, float* amax) {
    const float4* s4 = (const float4*)src;
    float m = 0.f;
    long long stride = (long long)gridDim.x * blockDim.x;
    for (long long i = (long long)blockIdx.x * blockDim.x + threadIdx.x; i < n4; i += stride) {
        float4 v = s4[i];
        m = fmaxf(m, fmaxf(fmaxf(fabsf(v.x), fabsf(v.y)), fmaxf(fabsf(v.z), fabsf(v.w))));
    }
    __shared__ float sred[4];
    m = blockReduceMax(m, sred);
    if (threadIdx.x == 0) atomicMaxF(amax, m);
}

// LayerNorm, recompute-fused quantization:
// MODE 0: compute LN(fq?(x)) row, accumulate global amax only (no store)
// MODE 1: recompute LN identically, write i8 levels with s(amQ)
template <int MODE>
__global__ __launch_bounds__(256) void ln_kernel(
    const float* __restrict__ x, const float* __restrict__ g,
    const float* __restrict__ bb, signed char* __restrict__ dst,
    const float* __restrict__ amIn, const float* __restrict__ amQ,
    float* amax) {
    __shared__ float sred[4];
    int row = blockIdx.x;
    int t = threadIdx.x;
    const float4* xr = (const float4*)(x + (size_t)row * CDIM);
    float4 v = xr[t];
    if (amIn) {
        float s = scale_of(amIn);
        v.x = fqv(v.x, s); v.y = fqv(v.y, s); v.z = fqv(v.z, s); v.w = fqv(v.w, s);
    }
    float sum = blockReduceSum(v.x + v.y + v.z + v.w, sred);
    float mu = sum * (1.0f / CDIM);
    float dx = v.x - mu, dy = v.y - mu, dz = v.z - mu, dw = v.w - mu;
    float var = blockReduceSum(dx * dx + dy * dy + dz * dz + dw * dw, sred) * (1.0f / CDIM);
    float rstd = rsqrtf(var + 1e-6f);
    float4 gv = ((const float4*)g)[t], bv = ((const float4*)bb)[t];
    float4 o;
    o.x = dx * rstd * gv.x + bv.x;
    o.y = dy * rstd * gv.y + bv.y;
    o.z = dz * rstd * gv.z + bv.z;
    o.w = dw * rstd * gv.w + bv.w;
    if (MODE == 0) {
        float m = fmaxf(fmaxf(fabsf(o.x), fabsf(o.y)), fmaxf(fabsf(o.z), fabsf(o.w)));
        m = blockReduceMax(m, sred);
        if (t == 0) atomicMaxF(amax, m);
    } else {
        float s = scale_of(amQ);
        int q0 = (int)fminf(fmaxf(rintf(o.x / s), -127.f), 127.f);
        int q1 = (int)fminf(fmaxf(rintf(o.y / s), -127.f), 127.f);
        int q2 = (int)fminf(fmaxf(rintf(o.z / s), -127.f), 127.f);
        int q3 = (int)fminf(fmaxf(rintf(o.w / s), -127.f), 127.f);
        ((int*)dst)[(size_t)row * (CDIM / 4) + t] =
            (q0 & 255) | ((q1 & 255) << 8) | ((q2 & 255) << 16) | (q3 << 24);
    }
}

__global__ __launch_bounds__(256) void fq_inplace_kernel(float* __restrict__ buf, long long n4,
                                                         const float* __restrict__ am,
                                                         float* amOut) {
    float s = scale_of(am);
    float4* b4 = (float4*)buf;
    float m = 0.f;
    long long stride = (long long)gridDim.x * blockDim.x;
    for (long long i = (long long)blockIdx.x * blockDim.x + threadIdx.x; i < n4; i += stride) {
        float4 v = b4[i];
        v.x = fqv(v.x, s); v.y = fqv(v.y, s); v.z = fqv(v.z, s); v.w = fqv(v.w, s);
        b4[i] = v;
        m = fmaxf(m, fmaxf(fmaxf(fabsf(v.x), fabsf(v.y)), fmaxf(fabsf(v.z), fabsf(v.w))));
    }
    if (amOut) {
        __shared__ float sred[4];
        m = blockReduceMax(m, sred);
        if (threadIdx.x == 0) atomicMaxF(amOut, m);
    }
}

// buf[i] = FQ?(xin[i]) + fq(buf[i], s(am)); amOut = max|buf| (FQ applied if amX!=null)
__global__ __launch_bounds__(256) void addfq_kernel(const float* __restrict__ xin,
                                                    const float* __restrict__ amX,
                                                    float* __restrict__ buf, long long n4,
                                                    const float* __restrict__ am, float* amOut) {
    float s = scale_of(am);
    float sx = amX ? scale_of(amX) : 0.f;
    const float4* x4 = (const float4*)xin;
    float4* b4 = (float4*)buf;
    float m = 0.f;
    long long stride = (long long)gridDim.x * blockDim.x;
    for (long long i = (long long)blockIdx.x * blockDim.x + threadIdx.x; i < n4; i += stride) {
        float4 v = x4[i];
        if (amX) { v.x = fqv(v.x, sx); v.y = fqv(v.y, sx); v.z = fqv(v.z, sx); v.w = fqv(v.w, sx); }
        float4 u = b4[i];
        u.x = v.x + fqv(u.x, s);
        u.y = v.y + fqv(u.y, s);
        u.z = v.z + fqv(u.z, s);
        u.w = v.w + fqv(u.w, s);
        b4[i] = u;
        m = fmaxf(m, fmaxf(fmaxf(fabsf(u.x), fabsf(u.y)), fmaxf(fabsf(u.z), fabsf(u.w))));
    }
    __shared__ float sred[4];
    m = blockReduceMax(m, sred);
    if (threadIdx.x == 0) atomicMaxF(amOut, m);
}

// quantize to i8 levels: dst[i] = clamp(rint(src[i]/s), -127, 127), zeros for i>=n
__global__ __launch_bounds__(256) void quant_i8_kernel(const float* __restrict__ src,
                                                       signed char* __restrict__ dst,
                                                       long long n4, long long npad4,
                                                       const float* __restrict__ am) {
    float s = scale_of(am);
    long long stride = (long long)gridDim.x * blockDim.x;
    for (long long i = (long long)blockIdx.x * blockDim.x + threadIdx.x; i < npad4; i += stride) {
        float4 v = make_float4(0.f, 0.f, 0.f, 0.f);
        if (i < n4) v = ((const float4*)src)[i];
        int q0 = (int)fminf(fmaxf(rintf(v.x / s), -127.f), 127.f);
        int q1 = (int)fminf(fmaxf(rintf(v.y / s), -127.f), 127.f);
        int q2 = (int)fminf(fmaxf(rintf(v.z / s), -127.f), 127.f);
        int q3 = (int)fminf(fmaxf(rintf(v.w / s), -127.f), 127.f);
        ((int*)dst)[i] = (q0 & 255) | ((q1 & 255) << 8) | ((q2 & 255) << 16) | (q3 << 24);
    }
}

// quantize to bf16 integer levels (attention inputs)
__global__ __launch_bounds__(256) void quant_bf16_kernel(const float* __restrict__ src,
                                                         short* __restrict__ dst,
                                                         long long n4, long long npad4,
                                                         const float* __restrict__ am) {
    float s = scale_of(am);
    long long stride = (long long)gridDim.x * blockDim.x;
    for (long long i = (long long)blockIdx.x * blockDim.x + threadIdx.x; i < npad4; i += stride) {
        float4 v = make_float4(0.f, 0.f, 0.f, 0.f);
        if (i < n4) v = ((const float4*)src)[i];
        float qx = fminf(fmaxf(rintf(v.x / s), -127.f), 127.f);
        float qy = fminf(fmaxf(rintf(v.y / s), -127.f), 127.f);
        float qz = fminf(fmaxf(rintf(v.z / s), -127.f), 127.f);
        float qw = fminf(fmaxf(rintf(v.w / s), -127.f), 127.f);
        short4 o;
        o.x = bf16_of_small_int(qx);
        o.y = bf16_of_small_int(qy);
        o.z = bf16_of_small_int(qz);
        o.w = bf16_of_small_int(qw);
        ((short4*)dst)[i] = o;
    }
}

// transpose V levels: qkvq[b*197+m][2048+h*64+d] -> vtq[z][d][m] (stride KPAD)
__global__ __launch_bounds__(256) void vt_kernel(const short* __restrict__ qkvq,
                                                 short* __restrict__ vtq) {
    __shared__ short T[NSEQ * 65];
    int z = blockIdx.x, b = z >> 4, hh = z & 15;
    int tid = threadIdx.x;
    const short* vbase = qkvq + (size_t)b * NSEQ * QKVD + 2048 + hh * 64;
    for (int c = tid; c < NSEQ * 8; c += 256) {
        int m = c >> 3, piece = c & 7;
        bf16x8 v = *(const bf16x8*)&vbase[(size_t)m * QKVD + piece * 8];
        #pragma unroll
        for (int jj = 0; jj < 8; jj++) T[m * 65 + piece * 8 + jj] = v[jj];
    }
    __syncthreads();
    short* obase = vtq + (size_t)z * 64 * KPAD;
    for (int c = tid; c < 64 * (KPAD / 8); c += 256) {
        int d = c / (KPAD / 8), mc = c % (KPAD / 8);
        bf16x8 o;
        #pragma unroll
        for (int jj = 0; jj < 8; jj++) {
            int m = mc * 8 + jj;
            o[jj] = (m < NSEQ) ? T[m * 65 + d] : (short)0;
        }
        *(bf16x8*)&obase[(size_t)d * KPAD + mc * 8] = o;
    }
}

// wave-per-row softmax: fq(S row) -> softmax -> P levels (rint(p*255), bf16), pad to KPAD
__global__ __launch_bounds__(256) void softmax_kernel(const float* __restrict__ S,
                                                      short* __restrict__ pq,
                                                      const float* __restrict__ am) {
    int wave = threadIdx.x >> 6, lane = threadIdx.x & 63;
    long long row = (long long)blockIdx.x * 4 + wave;
    if (row >= (long long)NBH * NSEQ) return;
    int z = (int)(row / NSEQ), r = (int)(row % NSEQ);
    const float* src = S + (size_t)z * SSZ + (size_t)r * NSEQ;
    short* dst = pq + ((size_t)z * NSEQ + r) * KPAD;
    float s = scale_of(am);
    float v[4], mx = -3.0e38f;
    #pragma unroll
    for (int i = 0; i < 4; i++) {
        int c = lane + i * 64;
        v[i] = (c < NSEQ) ? fqv(src[c], s) : -3.0e38f;
        mx = fmaxf(mx, v[i]);
    }
    #pragma unroll
    for (int o = 32; o > 0; o >>= 1) mx = fmaxf(mx, __shfl_xor(mx, o));
    float e[4], sum = 0.f;
    #pragma unroll
    for (int i = 0; i < 4; i++) {
        int c = lane + i * 64;
        e[i] = (c < NSEQ) ? expf(v[i] - mx) : 0.f;
        sum += e[i];
    }
    #pragma unroll
    for (int o = 32; o > 0; o >>= 1) sum += __shfl_xor(sum, o);
    #pragma unroll
    for (int i = 0; i < 4; i++) {
        int c = lane + i * 64;
        if (c < KPAD) {
            float plvl = (c < NSEQ) ? rintf(e[i] / sum * 255.0f) : 0.f;
            dst[c] = bf16_of_small_int(plvl);
        }
    }
}

// ---------- i8 MFMA GEMM: C[M,N] = (Aq[Mpad,K] @ Bq[N,K]^T) * sA*sB + bias ----------
// 3-buffer pipeline with COUNTED vmcnt (T3+T4): stage tile t+2, waitcnt vmcnt(8)
// (drains only oldest 4 = current buffer's loads), raw s_barrier, compute, barrier.
// Loads never drain to 0 in the loop. 4-slot XOR swizzle as before. LDS 48KB ->
// 3 blocks/CU. XCD-chunked swizzle on 1D grid (grid % 8 == 0). K % 64 == 0, K/64 >= 3.
#define GLL(gp, lp) __builtin_amdgcn_global_load_lds( \
    (const __attribute__((address_space(1))) void*)(gp), \
    (__attribute__((address_space(3))) void*)(lp), 16, 0, 0)

template <int EPI>  // 0: scale+bias, 1: scale+bias+gelu
__global__ __launch_bounds__(256, 3) void mfma_gemm_kernel(
    const signed char* __restrict__ Aq, const signed char* __restrict__ Bq,
    const float* __restrict__ bias, float* __restrict__ C,
    int M, int N, int K, int NBX,
    const float* __restrict__ amA, const float* __restrict__ amB,
    float* __restrict__ amOut) {
    __shared__ __align__(16) signed char As[3][128 * 64];
    __shared__ __align__(16) signed char Bs[3][128 * 64];
    __shared__ float sred[4];
    const int tid = threadIdx.x;
    const int lane = tid & 63;
    const int wave = tid >> 6;
    const int wg = (blockIdx.x & 7) * ((int)gridDim.x >> 3) + ((int)blockIdx.x >> 3);
    const int n0 = (wg % NBX) * 128;
    const int m0 = (wg / NBX) * 128;
    const int wm = (wave >> 1) * 64;
    const int wn = (wave & 1) * 64;
    const float sAB = fmaxf(amA[0] / 127.0f, 1e-8f) * fmaxf(amB[0] / 127.0f, 1e-8f);

    i32x4 acc[4][4] = {};

    // staging: tile 128 rows x 64 i8 (4 slots x 16B). chunks s = tid, tid+256:
    // row = s>>2, phys slot s&3 holds global slot (s&3)^(row&3). LDS dest linear.
    const signed char* gA[2];
    const signed char* gB[2];
    #pragma unroll
    for (int i = 0; i < 2; i++) {
        int s = tid + 256 * i;
        int row = s >> 2;
        int gsl = ((s & 3) ^ (row & 3)) * 16;
        gA[i] = Aq + (size_t)(m0 + row) * K + gsl;
        gB[i] = Bq + (size_t)(n0 + row) * K + gsl;
    }
    const int lr = lane & 15;
    const int klane = lane >> 4;
    int offA[4], offB[4];
    #pragma unroll
    for (int i = 0; i < 4; i++) {
        int ra = wm + i * 16 + lr;
        int rb = wn + i * 16 + lr;
        offA[i] = ra * 64 + ((klane ^ (ra & 3)) * 16);
        offB[i] = rb * 64 + ((klane ^ (rb & 3)) * 16);
    }

    // drain pre-loop VMEM (amA/amB loads) so in-loop vmcnt counts only staging ops
    asm volatile("s_waitcnt vmcnt(0)" ::: "memory");

#define STAGE(buf, kk) do { \
    _Pragma("unroll") \
    for (int i = 0; i < 2; i++) { \
        GLL(gA[i] + (kk), &As[buf][wave * 1024 + i * 4096]); \
        GLL(gB[i] + (kk), &Bs[buf][wave * 1024 + i * 4096]); \
    } \
} while (0)

#define COMPUTE(buf) do { \
    i32x4 a[4], b[4]; \
    _Pragma("unroll") \
    for (int i = 0; i < 4; i++) { \
        a[i] = *(const i32x4*)&As[buf][offA[i]]; \
        b[i] = *(const i32x4*)&Bs[buf][offB[i]]; \
    } \
    __builtin_amdgcn_s_setprio(1); \
    _Pragma("unroll") \
    for (int i = 0; i < 4; i++) \
        _Pragma("unroll") \
        for (int j = 0; j < 4; j++) \
            acc[i][j] = __builtin_amdgcn_mfma_i32_16x16x64_i8(a[i], b[j], acc[i][j], 0, 0, 0); \
    __builtin_amdgcn_s_setprio(0); \
} while (0)

    const int NK = K >> 6;
    STAGE(0, 0);
    STAGE(1, 64);
    for (int t = 0; t < NK - 2; ++t) {
        STAGE((t + 2) % 3, (t + 2) << 6);
        // wait for buffer t's 4 loads (oldest); 8 newer loads stay in flight
        asm volatile("s_waitcnt vmcnt(8)" ::: "memory");
        __builtin_amdgcn_sched_barrier(0);
        __builtin_amdgcn_s_barrier();
        COMPUTE(t % 3);
        __builtin_amdgcn_s_barrier();  // all waves done reading buf t before overwrite
    }
    asm volatile("s_waitcnt vmcnt(4)" ::: "memory");
    __builtin_amdgcn_sched_barrier(0);
    __builtin_amdgcn_s_barrier();
    COMPUTE((NK - 2) % 3);
    asm volatile("s_waitcnt vmcnt(0)" ::: "memory");
    __builtin_amdgcn_sched_barrier(0);
    __builtin_amdgcn_s_barrier();
    COMPUTE((NK - 1) % 3);
#undef STAGE
#undef COMPUTE

    // epilogue: C/D layout col=lane&15, row=(lane>>4)*4+reg (dtype-independent)
    const int cr = (lane >> 4) * 4;
    const int cc = lane & 15;
    float mloc = 0.f;
    #pragma unroll
    for (int i = 0; i < 4; i++) {
        #pragma unroll
        for (int j = 0; j < 4; j++) {
            int gn = n0 + wn + j * 16 + cc;
            float bv = bias[gn];
            #pragma unroll
            for (int r = 0; r < 4; r++) {
                int gm = m0 + wm + i * 16 + cr + r;
                if (gm >= M) continue;
                float v = (float)acc[i][j][r] * sAB + bv;
                if (EPI == 1) v = gelu_f(v);
                C[(size_t)gm * N + gn] = v;
                mloc = fmaxf(mloc, fabsf(v));
            }
        }
    }
    mloc = blockReduceMax(mloc, sred);
    if (tid == 0) atomicMaxF(amOut, mloc);
}

// ---------- MFMA attention QK^T (bf16, unchanged) ----------
__global__ __launch_bounds__(256, 2) void attn_qk_kernel(
    const short* __restrict__ qkvq, float* __restrict__ S,
    const float* __restrict__ amQ, float* __restrict__ amOut) {
    __shared__ __align__(16) short Qs[256 * 32];
    __shared__ __align__(16) short Ks[64 * 32];
    __shared__ float sred[4];
    const int tid = threadIdx.x, lane = tid & 63, wave = tid >> 6;
    const int z = blockIdx.z, b = z >> 4, hh = z & 15;
    const int n0 = blockIdx.x * 64;
    const short* qbase = qkvq + (size_t)b * NSEQ * QKVD + hh * 64;
    const short* kbase = qbase + 1024;
    const float s5 = fmaxf(amQ[0] / 127.0f, 1e-8f);
    const float sc = s5 * s5 * 0.125f;

    f32x4 acc[4][4] = {};
    const int piece = (tid & 3) * 8;
    const short* srcA[4];
    #pragma unroll
    for (int i = 0; i < 4; i++) {
        int row = i * 64 + (tid >> 2);
        srcA[i] = qbase + (size_t)min(row, NSEQ - 1) * QKVD + piece;
    }
    const short* srcB = kbase + (size_t)min(n0 + (tid >> 2), NSEQ - 1) * QKVD + piece;
    const int lr = lane & 15;
    const int koff = (lane >> 4) * 8;

    for (int k0 = 0; k0 < 64; k0 += 32) {
        __syncthreads();
        #pragma unroll
        for (int i = 0; i < 4; i++) GLL(srcA[i] + k0, Qs + i * 2048 + wave * 512);
        GLL(srcB + k0, Ks + wave * 512);
        __syncthreads();

        bf16x8 a[4], bfr[4];
        #pragma unroll
        for (int i = 0; i < 4; i++)
            a[i] = *(const bf16x8*)&Qs[(wave * 64 + i * 16 + lr) * 32 + koff];
        #pragma unroll
        for (int j = 0; j < 4; j++)
            bfr[j] = *(const bf16x8*)&Ks[(j * 16 + lr) * 32 + koff];
        #pragma unroll
        for (int i = 0; i < 4; i++)
            #pragma unroll
            for (int j = 0; j < 4; j++)
                acc[i][j] = __builtin_amdgcn_mfma_f32_16x16x32_bf16(a[i], bfr[j], acc[i][j], 0, 0, 0);
    }

    const int cr = (lane >> 4) * 4;
    const int cc = lane & 15;
    float* sbase = S + (size_t)z * SSZ;
    float mloc = 0.f;
    #pragma unroll
    for (int i = 0; i < 4; i++) {
        #pragma unroll
        for (int j = 0; j < 4; j++) {
            int gn = n0 + j * 16 + cc;
            #pragma unroll
            for (int r = 0; r < 4; r++) {
                int gm = wave * 64 + i * 16 + cr + r;
                if (gm < NSEQ && gn < NSEQ) {
                    float v = acc[i][j][r] * sc;
                    sbase[(size_t)gm * NSEQ + gn] = v;
                    mloc = fmaxf(mloc, fabsf(v));
                }
            }
        }
    }
    mloc = blockReduceMax(mloc, sred);
    if (tid == 0) atomicMaxF(amOut, mloc);
}

// ---------- MFMA attention PV (bf16, unchanged) ----------
__global__ __launch_bounds__(256, 2) void attn_pv_kernel(
    const short* __restrict__ pq, const short* __restrict__ vtq,
    float* __restrict__ xa,
    const float* __restrict__ amV, float* __restrict__ amOut) {
    __shared__ __align__(16) short Ps[256 * 32];
    __shared__ __align__(16) short Vs[64 * 32];
    __shared__ float sred[4];
    const int tid = threadIdx.x, lane = tid & 63, wave = tid >> 6;
    const int z = blockIdx.z, b = z >> 4, hh = z & 15;
    const short* pbase = pq + (size_t)z * NSEQ * KPAD;
    const short* vbase = vtq + (size_t)z * 64 * KPAD;
    const float sc = fmaxf(amV[0] / 127.0f, 1e-8f) * (1.0f / 255.0f);

    f32x4 acc[4][4] = {};
    const int piece = (tid & 3) * 8;
    const short* srcA[4];
    #pragma unroll
    for (int i = 0; i < 4; i++) {
        int row = i * 64 + (tid >> 2);
        srcA[i] = pbase + (size_t)min(row, NSEQ - 1) * KPAD + piece;
    }
    const short* srcB = vbase + (size_t)(tid >> 2) * KPAD + piece;
    const int lr = lane & 15;
    const int koff = (lane >> 4) * 8;

    for (int k0 = 0; k0 < KPAD; k0 += 32) {
        __syncthreads();
        #pragma unroll
        for (int i = 0; i < 4; i++) GLL(srcA[i] + k0, Ps + i * 2048 + wave * 512);
        GLL(srcB + k0, Vs + wave * 512);
        __syncthreads();

        bf16x8 a[4], bfr[4];
        #pragma unroll
        for (int i = 0; i < 4; i++)
            a[i] = *(const bf16x8*)&Ps[(wave * 64 + i * 16 + lr) * 32 + koff];
        #pragma unroll
        for (int j = 0; j < 4; j++)
            bfr[j] = *(const bf16x8*)&Vs[(j * 16 + lr) * 32 + koff];
        #pragma unroll
        for (int i = 0; i < 4; i++)
            #pragma unroll
            for (int j = 0; j < 4; j++)
                acc[i][j] = __builtin_amdgcn_mfma_f32_16x16x32_bf16(a[i], bfr[j], acc[i][j], 0, 0, 0);
    }

    const int cr = (lane >> 4) * 4;
    const int cc = lane & 15;
    float mloc = 0.f;
    #pragma unroll
    for (int i = 0; i < 4; i++) {
        #pragma unroll
        for (int j = 0; j < 4; j++) {
            int gn = j * 16 + cc;
            #pragma unroll
            for (int r = 0; r < 4; r++) {
                int gm = wave * 64 + i * 16 + cr + r;
                if (gm < NSEQ) {
                    float v = acc[i][j][r] * sc;
                    xa[((size_t)b * NSEQ + gm) * CDIM + hh * 64 + gn] = v;
                    mloc = fmaxf(mloc, fabsf(v));
                }
            }
        }
    }
    mloc = blockReduceMax(mloc, sred);
    if (tid == 0) atomicMaxF(amOut, mloc);
}

// ---------- launcher ----------
extern "C" void kernel_launch(void* const* d_in, const int* in_sizes, int n_in,
                              void* d_out, int out_size, void* d_ws, size_t ws_size,
                              hipStream_t stream) {
    (void)in_sizes; (void)n_in; (void)out_size; (void)ws_size;
    const float* x      = (const float*)d_in[0];
    const float* g1     = (const float*)d_in[1];
    const float* b1     = (const float*)d_in[2];
    const float* w_qkv  = (const float*)d_in[3];
    const float* b_qkv  = (const float*)d_in[4];
    const float* w_proj = (const float*)d_in[5];
    const float* b_proj = (const float*)d_in[6];
    const float* g2     = (const float*)d_in[7];
    const float* b2     = (const float*)d_in[8];
    const float* w_fc1  = (const float*)d_in[9];
    const float* b_fc1  = (const float*)d_in[10];
    const float* w_fc2  = (const float*)d_in[11];
    const float* b_fc2  = (const float*)d_in[12];
    float* out = (float*)d_out;
    float* ws  = (float*)d_ws;

    // amax slots: 0 wqkv 1 wproj 2 wfc1 3 wfc2 4 xn1 5 qkvout 6 attn 7 xa
    //             8 projout 9 x1 10 xn2 11 gelu(=h1) 13 fc2out 14 final
    float* am            = ws;
    signed char* wq_qkv  = (signed char*)(ws + 64);
    signed char* wq_proj = wq_qkv + (size_t)QKVD * CDIM;
    signed char* wq_fc1  = wq_proj + (size_t)CDIM * CDIM;
    signed char* wq_fc2  = wq_fc1 + (size_t)FFD * CDIM;
    signed char* xnq     = wq_fc2 + (size_t)CDIM * FFD;       // MPAD*CDIM i8
    float* y             = (float*)(xnq + (size_t)MPAD * CDIM);
    short* qkvq          = (short*)(y + (size_t)ROWS * CDIM); // ROWS*QKVD bf16
    float* R             = (float*)(qkvq + (size_t)ROWS * QKVD);
    float* qkvF          = R;                                 // ROWS*QKVD f32
    float* S             = R;                                 // NBH*SSZ f32
    short* pq            = (short*)(S + (size_t)NBH * SSZ);   // NBH*NSEQ*KPAD bf16
    short* vtq           = (short*)y;                         // aliases y
    float* h             = (float*)qkvq;                      // ROWS*FFD f32 (attn dead)
    signed char* hq      = (signed char*)(h + (size_t)ROWS * FFD); // MPAD*FFD i8
    float* xa = out;

    hipMemsetAsync(am, 0, 64 * sizeof(float), stream);
    // zero xnq pad rows once (ln_kernel<1> writes only ROWS rows; xa-quant re-zeros later)
    hipMemsetAsync(xnq + (size_t)ROWS * CDIM, 0, (size_t)(MPAD - ROWS) * CDIM, stream);

    absmax_kernel<<<2048, 256, 0, stream>>>(w_qkv, (long long)QKVD * CDIM / 4, am + 0);
    absmax_kernel<<<1024, 256, 0, stream>>>(w_proj, (long long)CDIM * CDIM / 4, am + 1);
    absmax_kernel<<<2048, 256, 0, stream>>>(w_fc1, (long long)FFD * CDIM / 4, am + 2);
    absmax_kernel<<<2048, 256, 0, stream>>>(w_fc2, (long long)CDIM * FFD / 4, am + 3);

    quant_i8_kernel<<<2048, 256, 0, stream>>>(w_qkv, wq_qkv,
        (long long)QKVD * CDIM / 4, (long long)QKVD * CDIM / 4, am + 0);
    quant_i8_kernel<<<1024, 256, 0, stream>>>(w_proj, wq_proj,
        (long long)CDIM * CDIM / 4, (long long)CDIM * CDIM / 4, am + 1);
    quant_i8_kernel<<<2048, 256, 0, stream>>>(w_fc1, wq_fc1,
        (long long)FFD * CDIM / 4, (long long)FFD * CDIM / 4, am + 2);
    quant_i8_kernel<<<2048, 256, 0, stream>>>(w_fc2, wq_fc2,
        (long long)CDIM * FFD / 4, (long long)CDIM * FFD / 4, am + 3);

    // LN1: amax pass + recompute-quant pass (no f32 intermediate)
    ln_kernel<0><<<ROWS, 256, 0, stream>>>(x, g1, b1, nullptr, nullptr, nullptr, am + 4);
    ln_kernel<1><<<ROWS, 256, 0, stream>>>(x, g1, b1, xnq, nullptr, am + 4, nullptr);

    // qkv = lvl(xn) @ lvl(w_qkv)^T * sA*sB + b_qkv   (grid 24x50 = 1200)
    mfma_gemm_kernel<0><<<1200, 256, 0, stream>>>(
        xnq, wq_qkv, b_qkv, qkvF, ROWS, QKVD, CDIM, QKVD / 128, am + 4, am + 0, am + 5);
    quant_bf16_kernel<<<2048, 256, 0, stream>>>(qkvF, qkvq,
        (long long)ROWS * QKVD / 4, (long long)ROWS * QKVD / 4, am + 5);
    vt_kernel<<<NBH, 256, 0, stream>>>(qkvq, vtq);

    // S = Q @ K^T * 0.125 (exact int MFMA), fused amax -> am6
    attn_qk_kernel<<<dim3(4, 1, NBH), 256, 0, stream>>>(qkvq, S, am + 5, am + 6);
    softmax_kernel<<<(NBH * NSEQ + 3) / 4, 256, 0, stream>>>(S, pq, am + 6);
    attn_pv_kernel<<<dim3(1, 1, NBH), 256, 0, stream>>>(pq, vtq, xa, am + 5, am + 7);

    // proj (grid 8x50 = 400)
    quant_i8_kernel<<<2048, 256, 0, stream>>>(xa, xnq,
        (long long)ROWS * CDIM / 4, (long long)MPAD * CDIM / 4, am + 7);
    mfma_gemm_kernel<0><<<400, 256, 0, stream>>>(
        xnq, wq_proj, b_proj, y, ROWS, CDIM, CDIM, CDIM / 128, am + 7, am + 1, am + 8);

    // residual 1: y = x + fq8(y); am9 = max|y|  (fq9 applied on-the-fly by consumers)
    addfq_kernel<<<2048, 256, 0, stream>>>(x, nullptr, y, (long long)ROWS * CDIM / 4,
                                           am + 8, am + 9);

    // LN2 (fused fq9 on load): amax pass + recompute-quant pass
    ln_kernel<0><<<ROWS, 256, 0, stream>>>(y, g2, b2, nullptr, am + 9, nullptr, am + 10);
    ln_kernel<1><<<ROWS, 256, 0, stream>>>(y, g2, b2, xnq, am + 9, am + 10, nullptr);

    // fc1 (+ gelu in epilogue; amax over gelu output -> am11)   (grid 32x50 = 1600)
    mfma_gemm_kernel<1><<<1600, 256, 0, stream>>>(
        xnq, wq_fc1, b_fc1, h, ROWS, FFD, CDIM, FFD / 128, am + 10, am + 2, am + 11);
    // h1 = fq(gelu); fq∘fq identity => quantize directly to i8 levels with s(am11)
    quant_i8_kernel<<<4096, 256, 0, stream>>>(h, hq,
        (long long)ROWS * FFD / 4, (long long)MPAD * FFD / 4, am + 11);

    // fc2 (grid 8x50 = 400), A-scale = am11 (== amax of h1 exactly)
    mfma_gemm_kernel<0><<<400, 256, 0, stream>>>(
        hq, wq_fc2, b_fc2, out, ROWS, CDIM, FFD, CDIM / 128, am + 11, am + 3, am + 13);

    // residual 2: out = fq9(y) + fq13(out); am14; final out = fq14(out)
    addfq_kernel<<<2048, 256, 0, stream>>>(y, am + 9, out, (long long)ROWS * CDIM / 4,
                                           am + 13, am + 14);
    fq_inplace_kernel<<<2048, 256, 0, stream>>>(out, (long long)ROWS * CDIM / 4, am + 14, nullptr);
}

// Round 9
// 711.390 us; speedup vs baseline: 1.0121x; 1.0121x over previous
//
#include <hip/hip_runtime.h>

#define ROWS 6304      // B*N = 32*197
#define MPAD 6400      // 50 * 128
#define CDIM 1024
#define QKVD 3072
#define FFD  4096
#define NSEQ 197
#define NBH  512       // B*H
#define SSZ  38809     // 197*197
#define KPAD 224       // attention K padded to 7*32

typedef __attribute__((ext_vector_type(8))) short bf16x8;
typedef __attribute__((ext_vector_type(4))) float f32x4;
typedef __attribute__((ext_vector_type(4))) int i32x4;

// ---------- device helpers ----------
__device__ __forceinline__ float fqv(float v, float s) {
    float q = rintf(v / s);
    q = fminf(fmaxf(q, -127.0f), 127.0f);
    return q * s;
}
__device__ __forceinline__ float scale_of(const float* am) {
    return fmaxf(am[0] / 127.0f, 1e-8f);
}
__device__ __forceinline__ float gelu_f(float x) {
    const float c = 0.7978845608028654f;  // sqrt(2/pi)
    float t = tanhf(c * (x + 0.044715f * x * x * x));
    return 0.5f * x * (1.0f + t);
}
__device__ __forceinline__ void atomicMaxF(float* p, float v) {
    atomicMax(reinterpret_cast<int*>(p), __float_as_int(v)); // v >= 0 always
}
__device__ __forceinline__ short bf16_of_small_int(float q) {
    return (short)(__float_as_uint(q) >> 16);  // exact for |q| <= 255 integers
}
// block = 256 threads (4 waves)
__device__ __forceinline__ float blockReduceSum(float v, float* sred) {
    int lane = threadIdx.x & 63, w = threadIdx.x >> 6;
    #pragma unroll
    for (int o = 32; o > 0; o >>= 1) v += __shfl_down(v, o);
    __syncthreads();
    if (lane == 0) sred[w] = v;
    __syncthreads();
    return sred[0] + sred[1] + sred[2] + sred[3];
}
__device__ __forceinline__ float blockReduceMax(float v, float* sred) {
    int lane = threadIdx.x & 63, w = threadIdx.x >> 6;
    #pragma unroll
    for (int o = 32; o > 0; o >>= 1) v = fmaxf(v, __shfl_down(v, o));
    __syncthreads();
    if (lane == 0) sred[w] = v;
    __syncthreads();
    return fmaxf(fmaxf(sred[0], sred[1]), fmaxf(sred[2], sred[3]));
}
// block = 512 threads (8 waves)
__device__ __forceinline__ float blockReduceMax8(float v, float* sred) {
    int lane = threadIdx.x & 63, w = threadIdx.x >> 6;
    #pragma unroll
    for (int o = 32; o > 0; o >>= 1) v = fmaxf(v, __shfl_down(v, o));
    __syncthreads();
    if (lane == 0) sred[w] = v;
    __syncthreads();
    float m = sred[0];
    #pragma unroll
    for (int i = 1; i < 8; i++) m = fmaxf(m, sred[i]);
    return m;
}

// ---------- elementwise / reduction kernels ----------
// merged absmax over 4 tensors (n in float4 units)
__global__ __launch_bounds__(256) void absmax4_kernel(
    const float* p0, long long n0, const float* p1, long long n1,
    const float* p2, long long n2, const float* p3, long long n3, float* am) {
    __shared__ float sred[4];
    const float* ps[4] = {p0, p1, p2, p3};
    long long ns[4] = {n0, n1, n2, n3};
    long long stride = (long long)gridDim.x * blockDim.x;
    for (int t = 0; t < 4; t++) {
        const float4* s4 = (const float4*)ps[t];
        float m = 0.f;
        for (long long i = (long long)blockIdx.x * blockDim.x + threadIdx.x; i < ns[t]; i += stride) {
            float4 v = s4[i];
            m = fmaxf(m, fmaxf(fmaxf(fabsf(v.x), fabsf(v.y)), fmaxf(fabsf(v.z), fabsf(v.w))));
        }
        m = blockReduceMax(m, sred);
        if (threadIdx.x == 0) atomicMaxF(am + t, m);
    }
}

// merged i8 quant of 4 tensors (scales am[t])
__global__ __launch_bounds__(256) void quant4_i8_kernel(
    const float* p0, signed char* d0, long long n0,
    const float* p1, signed char* d1, long long n1,
    const float* p2, signed char* d2, long long n2,
    const float* p3, signed char* d3, long long n3, const float* am) {
    const float* ps[4] = {p0, p1, p2, p3};
    signed char* ds[4] = {d0, d1, d2, d3};
    long long ns[4] = {n0, n1, n2, n3};
    long long stride = (long long)gridDim.x * blockDim.x;
    for (int t = 0; t < 4; t++) {
        float s = scale_of(am + t);
        for (long long i = (long long)blockIdx.x * blockDim.x + threadIdx.x; i < ns[t]; i += stride) {
            float4 v = ((const float4*)ps[t])[i];
            int q0 = (int)fminf(fmaxf(rintf(v.x / s), -127.f), 127.f);
            int q1 = (int)fminf(fmaxf(rintf(v.y / s), -127.f), 127.f);
            int q2 = (int)fminf(fmaxf(rintf(v.z / s), -127.f), 127.f);
            int q3 = (int)fminf(fmaxf(rintf(v.w / s), -127.f), 127.f);
            ((int*)ds[t])[i] = (q0 & 255) | ((q1 & 255) << 8) | ((q2 & 255) << 16) | (q3 << 24);
        }
    }
}

// LayerNorm, recompute-fused quantization:
// MODE 0: compute LN(fq?(x)) row, accumulate global amax only (no store)
// MODE 1: recompute LN identically, write i8 levels with s(amQ)
template <int MODE>
__global__ __launch_bounds__(256) void ln_kernel(
    const float* __restrict__ x, const float* __restrict__ g,
    const float* __restrict__ bb, signed char* __restrict__ dst,
    const float* __restrict__ amIn, const float* __restrict__ amQ,
    float* amax) {
    __shared__ float sred[4];
    int row = blockIdx.x;
    int t = threadIdx.x;
    const float4* xr = (const float4*)(x + (size_t)row * CDIM);
    float4 v = xr[t];
    if (amIn) {
        float s = scale_of(amIn);
        v.x = fqv(v.x, s); v.y = fqv(v.y, s); v.z = fqv(v.z, s); v.w = fqv(v.w, s);
    }
    float sum = blockReduceSum(v.x + v.y + v.z + v.w, sred);
    float mu = sum * (1.0f / CDIM);
    float dx = v.x - mu, dy = v.y - mu, dz = v.z - mu, dw = v.w - mu;
    float var = blockReduceSum(dx * dx + dy * dy + dz * dz + dw * dw, sred) * (1.0f / CDIM);
    float rstd = rsqrtf(var + 1e-6f);
    float4 gv = ((const float4*)g)[t], bv = ((const float4*)bb)[t];
    float4 o;
    o.x = dx * rstd * gv.x + bv.x;
    o.y = dy * rstd * gv.y + bv.y;
    o.z = dz * rstd * gv.z + bv.z;
    o.w = dw * rstd * gv.w + bv.w;
    if (MODE == 0) {
        float m = fmaxf(fmaxf(fabsf(o.x), fabsf(o.y)), fmaxf(fabsf(o.z), fabsf(o.w)));
        m = blockReduceMax(m, sred);
        if (t == 0) atomicMaxF(amax, m);
    } else {
        float s = scale_of(amQ);
        int q0 = (int)fminf(fmaxf(rintf(o.x / s), -127.f), 127.f);
        int q1 = (int)fminf(fmaxf(rintf(o.y / s), -127.f), 127.f);
        int q2 = (int)fminf(fmaxf(rintf(o.z / s), -127.f), 127.f);
        int q3 = (int)fminf(fmaxf(rintf(o.w / s), -127.f), 127.f);
        ((int*)dst)[(size_t)row * (CDIM / 4) + t] =
            (q0 & 255) | ((q1 & 255) << 8) | ((q2 & 255) << 16) | (q3 << 24);
    }
}

__global__ __launch_bounds__(256) void fq_inplace_kernel(float* __restrict__ buf, long long n4,
                                                         const float* __restrict__ am,
                                                         float* amOut) {
    float s = scale_of(am);
    float4* b4 = (float4*)buf;
    float m = 0.f;
    long long stride = (long long)gridDim.x * blockDim.x;
    for (long long i = (long long)blockIdx.x * blockDim.x + threadIdx.x; i < n4; i += stride) {
        float4 v = b4[i];
        v.x = fqv(v.x, s); v.y = fqv(v.y, s); v.z = fqv(v.z, s); v.w = fqv(v.w, s);
        b4[i] = v;
        m = fmaxf(m, fmaxf(fmaxf(fabsf(v.x), fabsf(v.y)), fmaxf(fabsf(v.z), fabsf(v.w))));
    }
    if (amOut) {
        __shared__ float sred[4];
        m = blockReduceMax(m, sred);
        if (threadIdx.x == 0) atomicMaxF(amOut, m);
    }
}

// buf[i] = FQ?(xin[i]) + fq(buf[i], s(am)); amOut = max|buf| (FQ applied if amX!=null)
__global__ __launch_bounds__(256) void addfq_kernel(const float* __restrict__ xin,
                                                    const float* __restrict__ amX,
                                                    float* __restrict__ buf, long long n4,
                                                    const float* __restrict__ am, float* amOut) {
    float s = scale_of(am);
    float sx = amX ? scale_of(amX) : 0.f;
    const float4* x4 = (const float4*)xin;
    float4* b4 = (float4*)buf;
    float m = 0.f;
    long long stride = (long long)gridDim.x * blockDim.x;
    for (long long i = (long long)blockIdx.x * blockDim.x + threadIdx.x; i < n4; i += stride) {
        float4 v = x4[i];
        if (amX) { v.x = fqv(v.x, sx); v.y = fqv(v.y, sx); v.z = fqv(v.z, sx); v.w = fqv(v.w, sx); }
        float4 u = b4[i];
        u.x = v.x + fqv(u.x, s);
        u.y = v.y + fqv(u.y, s);
        u.z = v.z + fqv(u.z, s);
        u.w = v.w + fqv(u.w, s);
        b4[i] = u;
        m = fmaxf(m, fmaxf(fmaxf(fabsf(u.x), fabsf(u.y)), fmaxf(fabsf(u.z), fabsf(u.w))));
    }
    __shared__ float sred[4];
    m = blockReduceMax(m, sred);
    if (threadIdx.x == 0) atomicMaxF(amOut, m);
}

// quantize to i8 levels, zeros for i>=n
__global__ __launch_bounds__(256) void quant_i8_kernel(const float* __restrict__ src,
                                                       signed char* __restrict__ dst,
                                                       long long n4, long long npad4,
                                                       const float* __restrict__ am) {
    float s = scale_of(am);
    long long stride = (long long)gridDim.x * blockDim.x;
    for (long long i = (long long)blockIdx.x * blockDim.x + threadIdx.x; i < npad4; i += stride) {
        float4 v = make_float4(0.f, 0.f, 0.f, 0.f);
        if (i < n4) v = ((const float4*)src)[i];
        int q0 = (int)fminf(fmaxf(rintf(v.x / s), -127.f), 127.f);
        int q1 = (int)fminf(fmaxf(rintf(v.y / s), -127.f), 127.f);
        int q2 = (int)fminf(fmaxf(rintf(v.z / s), -127.f), 127.f);
        int q3 = (int)fminf(fmaxf(rintf(v.w / s), -127.f), 127.f);
        ((int*)dst)[i] = (q0 & 255) | ((q1 & 255) << 8) | ((q2 & 255) << 16) | (q3 << 24);
    }
}

// quantize to bf16 integer levels (attention inputs)
__global__ __launch_bounds__(256) void quant_bf16_kernel(const float* __restrict__ src,
                                                         short* __restrict__ dst,
                                                         long long n4, long long npad4,
                                                         const float* __restrict__ am) {
    float s = scale_of(am);
    long long stride = (long long)gridDim.x * blockDim.x;
    for (long long i = (long long)blockIdx.x * blockDim.x + threadIdx.x; i < npad4; i += stride) {
        float4 v = make_float4(0.f, 0.f, 0.f, 0.f);
        if (i < n4) v = ((const float4*)src)[i];
        float qx = fminf(fmaxf(rintf(v.x / s), -127.f), 127.f);
        float qy = fminf(fmaxf(rintf(v.y / s), -127.f), 127.f);
        float qz = fminf(fmaxf(rintf(v.z / s), -127.f), 127.f);
        float qw = fminf(fmaxf(rintf(v.w / s), -127.f), 127.f);
        short4 o;
        o.x = bf16_of_small_int(qx);
        o.y = bf16_of_small_int(qy);
        o.z = bf16_of_small_int(qz);
        o.w = bf16_of_small_int(qw);
        ((short4*)dst)[i] = o;
    }
}

// transpose V levels: qkvq[b*197+m][2048+h*64+d] -> vtq[z][d][m] (stride KPAD)
__global__ __launch_bounds__(256) void vt_kernel(const short* __restrict__ qkvq,
                                                 short* __restrict__ vtq) {
    __shared__ short T[NSEQ * 65];
    int z = blockIdx.x, b = z >> 4, hh = z & 15;
    int tid = threadIdx.x;
    const short* vbase = qkvq + (size_t)b * NSEQ * QKVD + 2048 + hh * 64;
    for (int c = tid; c < NSEQ * 8; c += 256) {
        int m = c >> 3, piece = c & 7;
        bf16x8 v = *(const bf16x8*)&vbase[(size_t)m * QKVD + piece * 8];
        #pragma unroll
        for (int jj = 0; jj < 8; jj++) T[m * 65 + piece * 8 + jj] = v[jj];
    }
    __syncthreads();
    short* obase = vtq + (size_t)z * 64 * KPAD;
    for (int c = tid; c < 64 * (KPAD / 8); c += 256) {
        int d = c / (KPAD / 8), mc = c % (KPAD / 8);
        bf16x8 o;
        #pragma unroll
        for (int jj = 0; jj < 8; jj++) {
            int m = mc * 8 + jj;
            o[jj] = (m < NSEQ) ? T[m * 65 + d] : (short)0;
        }
        *(bf16x8*)&obase[(size_t)d * KPAD + mc * 8] = o;
    }
}

// wave-per-row softmax: fq(S row) -> softmax -> P levels (rint(p*255), bf16), pad to KPAD
__global__ __launch_bounds__(256) void softmax_kernel(const float* __restrict__ S,
                                                      short* __restrict__ pq,
                                                      const float* __restrict__ am) {
    int wave = threadIdx.x >> 6, lane = threadIdx.x & 63;
    long long row = (long long)blockIdx.x * 4 + wave;
    if (row >= (long long)NBH * NSEQ) return;
    int z = (int)(row / NSEQ), r = (int)(row % NSEQ);
    const float* src = S + (size_t)z * SSZ + (size_t)r * NSEQ;
    short* dst = pq + ((size_t)z * NSEQ + r) * KPAD;
    float s = scale_of(am);
    float v[4], mx = -3.0e38f;
    #pragma unroll
    for (int i = 0; i < 4; i++) {
        int c = lane + i * 64;
        v[i] = (c < NSEQ) ? fqv(src[c], s) : -3.0e38f;
        mx = fmaxf(mx, v[i]);
    }
    #pragma unroll
    for (int o = 32; o > 0; o >>= 1) mx = fmaxf(mx, __shfl_xor(mx, o));
    float e[4], sum = 0.f;
    #pragma unroll
    for (int i = 0; i < 4; i++) {
        int c = lane + i * 64;
        e[i] = (c < NSEQ) ? expf(v[i] - mx) : 0.f;
        sum += e[i];
    }
    #pragma unroll
    for (int o = 32; o > 0; o >>= 1) sum += __shfl_xor(sum, o);
    #pragma unroll
    for (int i = 0; i < 4; i++) {
        int c = lane + i * 64;
        if (c < KPAD) {
            float plvl = (c < NSEQ) ? rintf(e[i] / sum * 255.0f) : 0.f;
            dst[c] = bf16_of_small_int(plvl);
        }
    }
}

#define GLL(gp, lp) __builtin_amdgcn_global_load_lds( \
    (const __attribute__((address_space(1))) void*)(gp), \
    (__attribute__((address_space(3))) void*)(lp), 16, 0, 0)

// ---------- i8 MFMA GEMM, 4-wave 128x128 (round-7 proven structure) ----------
// 2-buffer, 2 barriers/K64-step, 4-slot XOR swizzle, LDS 32KB -> 4 blocks/CU.
template <int EPI>  // 0: scale+bias, 1: scale+bias+gelu
__global__ __launch_bounds__(256, 4) void mfma_gemm_kernel(
    const signed char* __restrict__ Aq, const signed char* __restrict__ Bq,
    const float* __restrict__ bias, float* __restrict__ C,
    int M, int N, int K, int NBX,
    const float* __restrict__ amA, const float* __restrict__ amB,
    float* __restrict__ amOut) {
    __shared__ __align__(16) signed char As[2][128 * 64];
    __shared__ __align__(16) signed char Bs[2][128 * 64];
    __shared__ float sred[4];
    const int tid = threadIdx.x;
    const int lane = tid & 63;
    const int wave = tid >> 6;
    const int wg = (blockIdx.x & 7) * ((int)gridDim.x >> 3) + ((int)blockIdx.x >> 3);
    const int n0 = (wg % NBX) * 128;
    const int m0 = (wg / NBX) * 128;
    const int wm = (wave >> 1) * 64;
    const int wn = (wave & 1) * 64;
    const float sAB = fmaxf(amA[0] / 127.0f, 1e-8f) * fmaxf(amB[0] / 127.0f, 1e-8f);

    i32x4 acc[4][4] = {};

    const signed char* gA[2];
    const signed char* gB[2];
    #pragma unroll
    for (int i = 0; i < 2; i++) {
        int s = tid + 256 * i;
        int row = s >> 2;
        int gsl = ((s & 3) ^ (row & 3)) * 16;
        gA[i] = Aq + (size_t)(m0 + row) * K + gsl;
        gB[i] = Bq + (size_t)(n0 + row) * K + gsl;
    }
    const int lr = lane & 15;
    const int klane = lane >> 4;
    int offA[4], offB[4];
    #pragma unroll
    for (int i = 0; i < 4; i++) {
        int ra = wm + i * 16 + lr;
        int rb = wn + i * 16 + lr;
        offA[i] = ra * 64 + ((klane ^ (ra & 3)) * 16);
        offB[i] = rb * 64 + ((klane ^ (rb & 3)) * 16);
    }

#define STAGE(buf, kk) do { \
    _Pragma("unroll") \
    for (int i = 0; i < 2; i++) { \
        GLL(gA[i] + (kk), &As[buf][wave * 1024 + i * 4096]); \
        GLL(gB[i] + (kk), &Bs[buf][wave * 1024 + i * 4096]); \
    } \
} while (0)

#define COMPUTE(buf) do { \
    i32x4 a[4], b[4]; \
    _Pragma("unroll") \
    for (int i = 0; i < 4; i++) { \
        a[i] = *(const i32x4*)&As[buf][offA[i]]; \
        b[i] = *(const i32x4*)&Bs[buf][offB[i]]; \
    } \
    _Pragma("unroll") \
    for (int i = 0; i < 4; i++) \
        _Pragma("unroll") \
        for (int j = 0; j < 4; j++) \
            acc[i][j] = __builtin_amdgcn_mfma_i32_16x16x64_i8(a[i], b[j], acc[i][j], 0, 0, 0); \
} while (0)

    STAGE(0, 0);
    __syncthreads();
    int k0 = 0;
    for (; k0 + 128 < K; k0 += 128) {
        STAGE(1, k0 + 64);
        COMPUTE(0);
        __syncthreads();
        STAGE(0, k0 + 128);
        COMPUTE(1);
        __syncthreads();
    }
    STAGE(1, k0 + 64);
    COMPUTE(0);
    __syncthreads();
    COMPUTE(1);
#undef STAGE
#undef COMPUTE

    const int cr = (lane >> 4) * 4;
    const int cc = lane & 15;
    float mloc = 0.f;
    #pragma unroll
    for (int i = 0; i < 4; i++) {
        #pragma unroll
        for (int j = 0; j < 4; j++) {
            int gn = n0 + wn + j * 16 + cc;
            float bv = bias[gn];
            #pragma unroll
            for (int r = 0; r < 4; r++) {
                int gm = m0 + wm + i * 16 + cr + r;
                if (gm >= M) continue;
                float v = (float)acc[i][j][r] * sAB + bv;
                if (EPI == 1) v = gelu_f(v);
                C[(size_t)gm * N + gn] = v;
                mloc = fmaxf(mloc, fabsf(v));
            }
        }
    }
    mloc = blockReduceMax(mloc, sred);
    if (tid == 0) atomicMaxF(amOut, mloc);
}

// ---------- i8 MFMA GEMM, 8-wave 256x128 (qkv, fc1) ----------
// Same wave-level inner loop (64x64, 16 MFMA, 4-slot XOR swizzle); 8 waves 4Mx2N.
// LDS 48KB (A 16KB + B 8KB, x2 buffers) -> 2-3 blocks/CU. Grid 1D %8, XCD swizzle.
template <int EPI>
__global__ __launch_bounds__(512, 4) void mfma_gemm8_kernel(
    const signed char* __restrict__ Aq, const signed char* __restrict__ Bq,
    const float* __restrict__ bias, float* __restrict__ C,
    int M, int N, int K, int NBX,
    const float* __restrict__ amA, const float* __restrict__ amB,
    float* __restrict__ amOut) {
    __shared__ __align__(16) signed char As[2][256 * 64];
    __shared__ __align__(16) signed char Bs[2][128 * 64];
    __shared__ float sred[8];
    const int tid = threadIdx.x;
    const int lane = tid & 63;
    const int wave = tid >> 6;           // 0..7
    const int wg = (blockIdx.x & 7) * ((int)gridDim.x >> 3) + ((int)blockIdx.x >> 3);
    const int n0 = (wg % NBX) * 128;
    const int m0 = (wg / NBX) * 256;
    const int wm = (wave >> 1) * 64;     // 0,64,128,192
    const int wn = (wave & 1) * 64;      // 0,64
    const float sAB = fmaxf(amA[0] / 127.0f, 1e-8f) * fmaxf(amB[0] / 127.0f, 1e-8f);

    i32x4 acc[4][4] = {};

    // A tile 256x64 = 2 chunks of 512x16B; B tile 128x64 = 1 chunk
    const signed char* gA[2];
    #pragma unroll
    for (int i = 0; i < 2; i++) {
        int s = tid + 512 * i;
        int row = s >> 2;
        int gsl = ((s & 3) ^ (row & 3)) * 16;
        gA[i] = Aq + (size_t)(m0 + row) * K + gsl;
    }
    const signed char* gB;
    {
        int row = tid >> 2;
        int gsl = ((tid & 3) ^ (row & 3)) * 16;
        gB = Bq + (size_t)(n0 + row) * K + gsl;
    }
    const int lr = lane & 15;
    const int klane = lane >> 4;
    int offA[4], offB[4];
    #pragma unroll
    for (int i = 0; i < 4; i++) {
        int ra = wm + i * 16 + lr;       // 0..255
        int rb = wn + i * 16 + lr;       // 0..127
        offA[i] = ra * 64 + ((klane ^ (ra & 3)) * 16);
        offB[i] = rb * 64 + ((klane ^ (rb & 3)) * 16);
    }

#define STAGE(buf, kk) do { \
    GLL(gA[0] + (kk), &As[buf][wave * 1024]); \
    GLL(gA[1] + (kk), &As[buf][wave * 1024 + 8192]); \
    GLL(gB + (kk),    &Bs[buf][wave * 1024]); \
} while (0)

#define COMPUTE(buf) do { \
    i32x4 a[4], b[4]; \
    _Pragma("unroll") \
    for (int i = 0; i < 4; i++) { \
        a[i] = *(const i32x4*)&As[buf][offA[i]]; \
        b[i] = *(const i32x4*)&Bs[buf][offB[i]]; \
    } \
    _Pragma("unroll") \
    for (int i = 0; i < 4; i++) \
        _Pragma("unroll") \
        for (int j = 0; j < 4; j++) \
            acc[i][j] = __builtin_amdgcn_mfma_i32_16x16x64_i8(a[i], b[j], acc[i][j], 0, 0, 0); \
} while (0)

    STAGE(0, 0);
    __syncthreads();
    int k0 = 0;
    for (; k0 + 128 < K; k0 += 128) {
        STAGE(1, k0 + 64);
        COMPUTE(0);
        __syncthreads();
        STAGE(0, k0 + 128);
        COMPUTE(1);
        __syncthreads();
    }
    STAGE(1, k0 + 64);
    COMPUTE(0);
    __syncthreads();
    COMPUTE(1);
#undef STAGE
#undef COMPUTE

    const int cr = (lane >> 4) * 4;
    const int cc = lane & 15;
    float mloc = 0.f;
    #pragma unroll
    for (int i = 0; i < 4; i++) {
        #pragma unroll
        for (int j = 0; j < 4; j++) {
            int gn = n0 + wn + j * 16 + cc;
            float bv = bias[gn];
            #pragma unroll
            for (int r = 0; r < 4; r++) {
                int gm = m0 + wm + i * 16 + cr + r;
                if (gm >= M) continue;
                float v = (float)acc[i][j][r] * sAB + bv;
                if (EPI == 1) v = gelu_f(v);
                C[(size_t)gm * N + gn] = v;
                mloc = fmaxf(mloc, fabsf(v));
            }
        }
    }
    mloc = blockReduceMax8(mloc, sred);
    if (tid == 0) atomicMaxF(amOut, mloc);
}

// ---------- MFMA attention QK^T (bf16) ----------
__global__ __launch_bounds__(256, 2) void attn_qk_kernel(
    const short* __restrict__ qkvq, float* __restrict__ S,
    const float* __restrict__ amQ, float* __restrict__ amOut) {
    __shared__ __align__(16) short Qs[256 * 32];
    __shared__ __align__(16) short Ks[64 * 32];
    __shared__ float sred[4];
    const int tid = threadIdx.x, lane = tid & 63, wave = tid >> 6;
    const int z = blockIdx.z, b = z >> 4, hh = z & 15;
    const int n0 = blockIdx.x * 64;
    const short* qbase = qkvq + (size_t)b * NSEQ * QKVD + hh * 64;
    const short* kbase = qbase + 1024;
    const float s5 = fmaxf(amQ[0] / 127.0f, 1e-8f);
    const float sc = s5 * s5 * 0.125f;

    f32x4 acc[4][4] = {};
    const int piece = (tid & 3) * 8;
    const short* srcA[4];
    #pragma unroll
    for (int i = 0; i < 4; i++) {
        int row = i * 64 + (tid >> 2);
        srcA[i] = qbase + (size_t)min(row, NSEQ - 1) * QKVD + piece;
    }
    const short* srcB = kbase + (size_t)min(n0 + (tid >> 2), NSEQ - 1) * QKVD + piece;
    const int lr = lane & 15;
    const int koff = (lane >> 4) * 8;

    for (int k0 = 0; k0 < 64; k0 += 32) {
        __syncthreads();
        #pragma unroll
        for (int i = 0; i < 4; i++) GLL(srcA[i] + k0, Qs + i * 2048 + wave * 512);
        GLL(srcB + k0, Ks + wave * 512);
        __syncthreads();

        bf16x8 a[4], bfr[4];
        #pragma unroll
        for (int i = 0; i < 4; i++)
            a[i] = *(const bf16x8*)&Qs[(wave * 64 + i * 16 + lr) * 32 + koff];
        #pragma unroll
        for (int j = 0; j < 4; j++)
            bfr[j] = *(const bf16x8*)&Ks[(j * 16 + lr) * 32 + koff];
        #pragma unroll
        for (int i = 0; i < 4; i++)
            #pragma unroll
            for (int j = 0; j < 4; j++)
                acc[i][j] = __builtin_amdgcn_mfma_f32_16x16x32_bf16(a[i], bfr[j], acc[i][j], 0, 0, 0);
    }

    const int cr = (lane >> 4) * 4;
    const int cc = lane & 15;
    float* sbase = S + (size_t)z * SSZ;
    float mloc = 0.f;
    #pragma unroll
    for (int i = 0; i < 4; i++) {
        #pragma unroll
        for (int j = 0; j < 4; j++) {
            int gn = n0 + j * 16 + cc;
            #pragma unroll
            for (int r = 0; r < 4; r++) {
                int gm = wave * 64 + i * 16 + cr + r;
                if (gm < NSEQ && gn < NSEQ) {
                    float v = acc[i][j][r] * sc;
                    sbase[(size_t)gm * NSEQ + gn] = v;
                    mloc = fmaxf(mloc, fabsf(v));
                }
            }
        }
    }
    mloc = blockReduceMax(mloc, sred);
    if (tid == 0) atomicMaxF(amOut, mloc);
}

// ---------- MFMA attention PV (bf16) ----------
__global__ __launch_bounds__(256, 2) void attn_pv_kernel(
    const short* __restrict__ pq, const short* __restrict__ vtq,
    float* __restrict__ xa,
    const float* __restrict__ amV, float* __restrict__ amOut) {
    __shared__ __align__(16) short Ps[256 * 32];
    __shared__ __align__(16) short Vs[64 * 32];
    __shared__ float sred[4];
    const int tid = threadIdx.x, lane = tid & 63, wave = tid >> 6;
    const int z = blockIdx.z, b = z >> 4, hh = z & 15;
    const short* pbase = pq + (size_t)z * NSEQ * KPAD;
    const short* vbase = vtq + (size_t)z * 64 * KPAD;
    const float sc = fmaxf(amV[0] / 127.0f, 1e-8f) * (1.0f / 255.0f);

    f32x4 acc[4][4] = {};
    const int piece = (tid & 3) * 8;
    const short* srcA[4];
    #pragma unroll
    for (int i = 0; i < 4; i++) {
        int row = i * 64 + (tid >> 2);
        srcA[i] = pbase + (size_t)min(row, NSEQ - 1) * KPAD + piece;
    }
    const short* srcB = vbase + (size_t)(tid >> 2) * KPAD + piece;
    const int lr = lane & 15;
    const int koff = (lane >> 4) * 8;

    for (int k0 = 0; k0 < KPAD; k0 += 32) {
        __syncthreads();
        #pragma unroll
        for (int i = 0; i < 4; i++) GLL(srcA[i] + k0, Ps + i * 2048 + wave * 512);
        GLL(srcB + k0, Vs + wave * 512);
        __syncthreads();

        bf16x8 a[4], bfr[4];
        #pragma unroll
        for (int i = 0; i < 4; i++)
            a[i] = *(const bf16x8*)&Ps[(wave * 64 + i * 16 + lr) * 32 + koff];
        #pragma unroll
        for (int j = 0; j < 4; j++)
            bfr[j] = *(const bf16x8*)&Vs[(j * 16 + lr) * 32 + koff];
        #pragma unroll
        for (int i = 0; i < 4; i++)
            #pragma unroll
            for (int j = 0; j < 4; j++)
                acc[i][j] = __builtin_amdgcn_mfma_f32_16x16x32_bf16(a[i], bfr[j], acc[i][j], 0, 0, 0);
    }

    const int cr = (lane >> 4) * 4;
    const int cc = lane & 15;
    float mloc = 0.f;
    #pragma unroll
    for (int i = 0; i < 4; i++) {
        #pragma unroll
        for (int j = 0; j < 4; j++) {
            int gn = j * 16 + cc;
            #pragma unroll
            for (int r = 0; r < 4; r++) {
                int gm = wave * 64 + i * 16 + cr + r;
                if (gm < NSEQ) {
                    float v = acc[i][j][r] * sc;
                    xa[((size_t)b * NSEQ + gm) * CDIM + hh * 64 + gn] = v;
                    mloc = fmaxf(mloc, fabsf(v));
                }
            }
        }
    }
    mloc = blockReduceMax(mloc, sred);
    if (tid == 0) atomicMaxF(amOut, mloc);
}

// ---------- launcher ----------
extern "C" void kernel_launch(void* const* d_in, const int* in_sizes, int n_in,
                              void* d_out, int out_size, void* d_ws, size_t ws_size,
                              hipStream_t stream) {
    (void)in_sizes; (void)n_in; (void)out_size; (void)ws_size;
    const float* x      = (const float*)d_in[0];
    const float* g1     = (const float*)d_in[1];
    const float* b1     = (const float*)d_in[2];
    const float* w_qkv  = (const float*)d_in[3];
    const float* b_qkv  = (const float*)d_in[4];
    const float* w_proj = (const float*)d_in[5];
    const float* b_proj = (const float*)d_in[6];
    const float* g2     = (const float*)d_in[7];
    const float* b2     = (const float*)d_in[8];
    const float* w_fc1  = (const float*)d_in[9];
    const float* b_fc1  = (const float*)d_in[10];
    const float* w_fc2  = (const float*)d_in[11];
    const float* b_fc2  = (const float*)d_in[12];
    float* out = (float*)d_out;
    float* ws  = (float*)d_ws;

    // amax slots: 0 wqkv 1 wproj 2 wfc1 3 wfc2 4 xn1 5 qkvout 6 attn 7 xa
    //             8 projout 9 x1 10 xn2 11 gelu(=h1) 13 fc2out 14 final
    float* am            = ws;
    signed char* wq_qkv  = (signed char*)(ws + 64);
    signed char* wq_proj = wq_qkv + (size_t)QKVD * CDIM;
    signed char* wq_fc1  = wq_proj + (size_t)CDIM * CDIM;
    signed char* wq_fc2  = wq_fc1 + (size_t)FFD * CDIM;
    signed char* xnq     = wq_fc2 + (size_t)CDIM * FFD;       // MPAD*CDIM i8
    float* y             = (float*)(xnq + (size_t)MPAD * CDIM);
    short* qkvq          = (short*)(y + (size_t)ROWS * CDIM); // ROWS*QKVD bf16
    float* R             = (float*)(qkvq + (size_t)ROWS * QKVD);
    float* qkvF          = R;                                 // ROWS*QKVD f32
    float* S             = R;                                 // NBH*SSZ f32
    short* pq            = (short*)(S + (size_t)NBH * SSZ);   // NBH*NSEQ*KPAD bf16
    short* vtq           = (short*)y;                         // aliases y
    float* h             = (float*)qkvq;                      // ROWS*FFD f32 (attn dead)
    signed char* hq      = (signed char*)(h + (size_t)ROWS * FFD); // MPAD*FFD i8
    float* xa = out;

    hipMemsetAsync(am, 0, 64 * sizeof(float), stream);
    hipMemsetAsync(xnq + (size_t)ROWS * CDIM, 0, (size_t)(MPAD - ROWS) * CDIM, stream);

    absmax4_kernel<<<2048, 256, 0, stream>>>(
        w_qkv, (long long)QKVD * CDIM / 4, w_proj, (long long)CDIM * CDIM / 4,
        w_fc1, (long long)FFD * CDIM / 4, w_fc2, (long long)CDIM * FFD / 4, am);
    quant4_i8_kernel<<<2048, 256, 0, stream>>>(
        w_qkv, wq_qkv, (long long)QKVD * CDIM / 4,
        w_proj, wq_proj, (long long)CDIM * CDIM / 4,
        w_fc1, wq_fc1, (long long)FFD * CDIM / 4,
        w_fc2, wq_fc2, (long long)CDIM * FFD / 4, am);

    // LN1: amax pass + recompute-quant pass (no f32 intermediate)
    ln_kernel<0><<<ROWS, 256, 0, stream>>>(x, g1, b1, nullptr, nullptr, nullptr, am + 4);
    ln_kernel<1><<<ROWS, 256, 0, stream>>>(x, g1, b1, xnq, nullptr, am + 4, nullptr);

    // qkv (8-wave 256x128, grid 25x24 = 600)
    mfma_gemm8_kernel<0><<<600, 512, 0, stream>>>(
        xnq, wq_qkv, b_qkv, qkvF, ROWS, QKVD, CDIM, QKVD / 128, am + 4, am + 0, am + 5);
    quant_bf16_kernel<<<2048, 256, 0, stream>>>(qkvF, qkvq,
        (long long)ROWS * QKVD / 4, (long long)ROWS * QKVD / 4, am + 5);
    vt_kernel<<<NBH, 256, 0, stream>>>(qkvq, vtq);

    // S = Q @ K^T * 0.125, fused amax -> am6
    attn_qk_kernel<<<dim3(4, 1, NBH), 256, 0, stream>>>(qkvq, S, am + 5, am + 6);
    softmax_kernel<<<(NBH * NSEQ + 3) / 4, 256, 0, stream>>>(S, pq, am + 6);
    attn_pv_kernel<<<dim3(1, 1, NBH), 256, 0, stream>>>(pq, vtq, xa, am + 5, am + 7);

    // proj (4-wave 128x128, grid 400)
    quant_i8_kernel<<<2048, 256, 0, stream>>>(xa, xnq,
        (long long)ROWS * CDIM / 4, (long long)MPAD * CDIM / 4, am + 7);
    mfma_gemm_kernel<0><<<400, 256, 0, stream>>>(
        xnq, wq_proj, b_proj, y, ROWS, CDIM, CDIM, CDIM / 128, am + 7, am + 1, am + 8);

    // residual 1: y = x + fq8(y); am9 = max|y|
    addfq_kernel<<<2048, 256, 0, stream>>>(x, nullptr, y, (long long)ROWS * CDIM / 4,
                                           am + 8, am + 9);

    // LN2 (fused fq9 on load): amax + recompute-quant
    ln_kernel<0><<<ROWS, 256, 0, stream>>>(y, g2, b2, nullptr, am + 9, nullptr, am + 10);
    ln_kernel<1><<<ROWS, 256, 0, stream>>>(y, g2, b2, xnq, am + 9, am + 10, nullptr);

    // fc1 (8-wave 256x128, grid 25x32 = 800; gelu epilogue, amax -> am11)
    mfma_gemm8_kernel<1><<<800, 512, 0, stream>>>(
        xnq, wq_fc1, b_fc1, h, ROWS, FFD, CDIM, FFD / 128, am + 10, am + 2, am + 11);
    // h1 = fq(gelu); fq∘fq identity => quantize directly with s(am11)
    quant_i8_kernel<<<4096, 256, 0, stream>>>(h, hq,
        (long long)ROWS * FFD / 4, (long long)MPAD * FFD / 4, am + 11);

    // fc2 (4-wave 128x128, grid 400)
    mfma_gemm_kernel<0><<<400, 256, 0, stream>>>(
        hq, wq_fc2, b_fc2, out, ROWS, CDIM, FFD, CDIM / 128, am + 11, am + 3, am + 13);

    // residual 2: out = fq9(y) + fq13(out); am14; final out = fq14(out)
    addfq_kernel<<<2048, 256, 0, stream>>>(y, am + 9, out, (long long)ROWS * CDIM / 4,
                                           am + 13, am + 14);
    fq_inplace_kernel<<<2048, 256, 0, stream>>>(out, (long long)ROWS * CDIM / 4, am + 14, nullptr);
}

// Round 10
// 645.699 us; speedup vs baseline: 1.1151x; 1.1017x over previous
//
#include <hip/hip_runtime.h>

#define ROWS 6304      // B*N = 32*197
#define MPAD 6400      // 50 * 128
#define CDIM 1024
#define QKVD 3072
#define FFD  4096
#define NSEQ 197
#define NBH  512       // B*H
#define SSZ  38809     // 197*197
#define KPAD 224       // attention K padded to 7*32

typedef __attribute__((ext_vector_type(8))) short bf16x8;
typedef __attribute__((ext_vector_type(4))) float f32x4;
typedef __attribute__((ext_vector_type(4))) int i32x4;

// ---------- device helpers ----------
__device__ __forceinline__ float fqv(float v, float s) {
    float q = rintf(v / s);
    q = fminf(fmaxf(q, -127.0f), 127.0f);
    return q * s;
}
__device__ __forceinline__ float scale_of(const float* am) {
    return fmaxf(am[0] / 127.0f, 1e-8f);
}
__device__ __forceinline__ float gelu_f(float x) {
    const float c = 0.7978845608028654f;  // sqrt(2/pi)
    float t = tanhf(c * (x + 0.044715f * x * x * x));
    return 0.5f * x * (1.0f + t);
}
__device__ __forceinline__ void atomicMaxF(float* p, float v) {
    atomicMax(reinterpret_cast<int*>(p), __float_as_int(v)); // v >= 0 always
}
__device__ __forceinline__ short bf16_of_small_int(float q) {
    return (short)(__float_as_uint(q) >> 16);  // exact for |q| <= 255 integers
}
// block = 256 threads (4 waves)
__device__ __forceinline__ float blockReduceSum(float v, float* sred) {
    int lane = threadIdx.x & 63, w = threadIdx.x >> 6;
    #pragma unroll
    for (int o = 32; o > 0; o >>= 1) v += __shfl_down(v, o);
    __syncthreads();
    if (lane == 0) sred[w] = v;
    __syncthreads();
    return sred[0] + sred[1] + sred[2] + sred[3];
}
__device__ __forceinline__ float blockReduceMax(float v, float* sred) {
    int lane = threadIdx.x & 63, w = threadIdx.x >> 6;
    #pragma unroll
    for (int o = 32; o > 0; o >>= 1) v = fmaxf(v, __shfl_down(v, o));
    __syncthreads();
    if (lane == 0) sred[w] = v;
    __syncthreads();
    return fmaxf(fmaxf(sred[0], sred[1]), fmaxf(sred[2], sred[3]));
}
// block = 512 threads (8 waves)
__device__ __forceinline__ float blockReduceMax8(float v, float* sred) {
    int lane = threadIdx.x & 63, w = threadIdx.x >> 6;
    #pragma unroll
    for (int o = 32; o > 0; o >>= 1) v = fmaxf(v, __shfl_down(v, o));
    __syncthreads();
    if (lane == 0) sred[w] = v;
    __syncthreads();
    float m = sred[0];
    #pragma unroll
    for (int i = 1; i < 8; i++) m = fmaxf(m, sred[i]);
    return m;
}

// ---------- weight prep: segment-parallel, static trip counts ----------
// grid = 3072 blocks: [0,768) w_qkv, [768,1024) w_proj, [1024,2048) fc1, [2048,3072) fc2.
// Every segment: exactly 4 coalesced float4 loads per thread (sizes are exact multiples).
__global__ __launch_bounds__(256) void wprep_absmax_kernel(
    const float* __restrict__ w0, const float* __restrict__ w1,
    const float* __restrict__ w2, const float* __restrict__ w3, float* am) {
    __shared__ float sred[4];
    int b = blockIdx.x, tid = threadIdx.x;
    const float4* p; int base, nb; float* amp;
    if (b < 768)       { p = (const float4*)w0; base = b;        nb = 768;  amp = am + 0; }
    else if (b < 1024) { p = (const float4*)w1; base = b - 768;  nb = 256;  amp = am + 1; }
    else if (b < 2048) { p = (const float4*)w2; base = b - 1024; nb = 1024; amp = am + 2; }
    else               { p = (const float4*)w3; base = b - 2048; nb = 1024; amp = am + 3; }
    float m = 0.f;
    #pragma unroll
    for (int it = 0; it < 4; it++) {
        float4 v = p[(long long)it * nb * 256 + (long long)base * 256 + tid];
        m = fmaxf(m, fmaxf(fmaxf(fabsf(v.x), fabsf(v.y)), fmaxf(fabsf(v.z), fabsf(v.w))));
    }
    m = blockReduceMax(m, sred);
    if (tid == 0) atomicMaxF(amp, m);
}

__global__ __launch_bounds__(256) void wprep_quant_kernel(
    const float* __restrict__ w0, signed char* __restrict__ d0,
    const float* __restrict__ w1, signed char* __restrict__ d1,
    const float* __restrict__ w2, signed char* __restrict__ d2,
    const float* __restrict__ w3, signed char* __restrict__ d3,
    const float* __restrict__ am) {
    int b = blockIdx.x, tid = threadIdx.x;
    const float4* p; int* d; int base, nb; float s;
    if (b < 768)       { p = (const float4*)w0; d = (int*)d0; base = b;        nb = 768;  s = scale_of(am + 0); }
    else if (b < 1024) { p = (const float4*)w1; d = (int*)d1; base = b - 768;  nb = 256;  s = scale_of(am + 1); }
    else if (b < 2048) { p = (const float4*)w2; d = (int*)d2; base = b - 1024; nb = 1024; s = scale_of(am + 2); }
    else               { p = (const float4*)w3; d = (int*)d3; base = b - 2048; nb = 1024; s = scale_of(am + 3); }
    #pragma unroll
    for (int it = 0; it < 4; it++) {
        long long i = (long long)it * nb * 256 + (long long)base * 256 + tid;
        float4 v = p[i];
        int q0 = (int)fminf(fmaxf(rintf(v.x / s), -127.f), 127.f);
        int q1 = (int)fminf(fmaxf(rintf(v.y / s), -127.f), 127.f);
        int q2 = (int)fminf(fmaxf(rintf(v.z / s), -127.f), 127.f);
        int q3 = (int)fminf(fmaxf(rintf(v.w / s), -127.f), 127.f);
        d[i] = (q0 & 255) | ((q1 & 255) << 8) | ((q2 & 255) << 16) | (q3 << 24);
    }
}

// ---------- LayerNorm, recompute-fused quantization ----------
// MODE 0: compute LN(fq?(x)) row, accumulate global amax only (no store)
// MODE 1: recompute LN identically, write i8 levels with s(amQ)
template <int MODE>
__global__ __launch_bounds__(256) void ln_kernel(
    const float* __restrict__ x, const float* __restrict__ g,
    const float* __restrict__ bb, signed char* __restrict__ dst,
    const float* __restrict__ amIn, const float* __restrict__ amQ,
    float* amax) {
    __shared__ float sred[4];
    int row = blockIdx.x;
    int t = threadIdx.x;
    const float4* xr = (const float4*)(x + (size_t)row * CDIM);
    float4 v = xr[t];
    if (amIn) {
        float s = scale_of(amIn);
        v.x = fqv(v.x, s); v.y = fqv(v.y, s); v.z = fqv(v.z, s); v.w = fqv(v.w, s);
    }
    float sum = blockReduceSum(v.x + v.y + v.z + v.w, sred);
    float mu = sum * (1.0f / CDIM);
    float dx = v.x - mu, dy = v.y - mu, dz = v.z - mu, dw = v.w - mu;
    float var = blockReduceSum(dx * dx + dy * dy + dz * dz + dw * dw, sred) * (1.0f / CDIM);
    float rstd = rsqrtf(var + 1e-6f);
    float4 gv = ((const float4*)g)[t], bv = ((const float4*)bb)[t];
    float4 o;
    o.x = dx * rstd * gv.x + bv.x;
    o.y = dy * rstd * gv.y + bv.y;
    o.z = dz * rstd * gv.z + bv.z;
    o.w = dw * rstd * gv.w + bv.w;
    if (MODE == 0) {
        float m = fmaxf(fmaxf(fabsf(o.x), fabsf(o.y)), fmaxf(fabsf(o.z), fabsf(o.w)));
        m = blockReduceMax(m, sred);
        if (t == 0) atomicMaxF(amax, m);
    } else {
        float s = scale_of(amQ);
        int q0 = (int)fminf(fmaxf(rintf(o.x / s), -127.f), 127.f);
        int q1 = (int)fminf(fmaxf(rintf(o.y / s), -127.f), 127.f);
        int q2 = (int)fminf(fmaxf(rintf(o.z / s), -127.f), 127.f);
        int q3 = (int)fminf(fmaxf(rintf(o.w / s), -127.f), 127.f);
        ((int*)dst)[(size_t)row * (CDIM / 4) + t] =
            (q0 & 255) | ((q1 & 255) << 8) | ((q2 & 255) << 16) | (q3 << 24);
    }
}

__global__ __launch_bounds__(256) void fq_inplace_kernel(float* __restrict__ buf, long long n4,
                                                         const float* __restrict__ am,
                                                         float* amOut) {
    float s = scale_of(am);
    float4* b4 = (float4*)buf;
    float m = 0.f;
    long long stride = (long long)gridDim.x * blockDim.x;
    for (long long i = (long long)blockIdx.x * blockDim.x + threadIdx.x; i < n4; i += stride) {
        float4 v = b4[i];
        v.x = fqv(v.x, s); v.y = fqv(v.y, s); v.z = fqv(v.z, s); v.w = fqv(v.w, s);
        b4[i] = v;
        m = fmaxf(m, fmaxf(fmaxf(fabsf(v.x), fabsf(v.y)), fmaxf(fabsf(v.z), fabsf(v.w))));
    }
    if (amOut) {
        __shared__ float sred[4];
        m = blockReduceMax(m, sred);
        if (threadIdx.x == 0) atomicMaxF(amOut, m);
    }
}

// buf[i] = FQ?(xin[i]) + fq(buf[i], s(am)); amOut = max|buf| (FQ applied if amX!=null)
__global__ __launch_bounds__(256) void addfq_kernel(const float* __restrict__ xin,
                                                    const float* __restrict__ amX,
                                                    float* __restrict__ buf, long long n4,
                                                    const float* __restrict__ am, float* amOut) {
    float s = scale_of(am);
    float sx = amX ? scale_of(amX) : 0.f;
    const float4* x4 = (const float4*)xin;
    float4* b4 = (float4*)buf;
    float m = 0.f;
    long long stride = (long long)gridDim.x * blockDim.x;
    for (long long i = (long long)blockIdx.x * blockDim.x + threadIdx.x; i < n4; i += stride) {
        float4 v = x4[i];
        if (amX) { v.x = fqv(v.x, sx); v.y = fqv(v.y, sx); v.z = fqv(v.z, sx); v.w = fqv(v.w, sx); }
        float4 u = b4[i];
        u.x = v.x + fqv(u.x, s);
        u.y = v.y + fqv(u.y, s);
        u.z = v.z + fqv(u.z, s);
        u.w = v.w + fqv(u.w, s);
        b4[i] = u;
        m = fmaxf(m, fmaxf(fmaxf(fabsf(u.x), fabsf(u.y)), fmaxf(fabsf(u.z), fabsf(u.w))));
    }
    __shared__ float sred[4];
    m = blockReduceMax(m, sred);
    if (threadIdx.x == 0) atomicMaxF(amOut, m);
}

// quantize to i8 levels, zeros for i>=n
__global__ __launch_bounds__(256) void quant_i8_kernel(const float* __restrict__ src,
                                                       signed char* __restrict__ dst,
                                                       long long n4, long long npad4,
                                                       const float* __restrict__ am) {
    float s = scale_of(am);
    long long stride = (long long)gridDim.x * blockDim.x;
    for (long long i = (long long)blockIdx.x * blockDim.x + threadIdx.x; i < npad4; i += stride) {
        float4 v = make_float4(0.f, 0.f, 0.f, 0.f);
        if (i < n4) v = ((const float4*)src)[i];
        int q0 = (int)fminf(fmaxf(rintf(v.x / s), -127.f), 127.f);
        int q1 = (int)fminf(fmaxf(rintf(v.y / s), -127.f), 127.f);
        int q2 = (int)fminf(fmaxf(rintf(v.z / s), -127.f), 127.f);
        int q3 = (int)fminf(fmaxf(rintf(v.w / s), -127.f), 127.f);
        ((int*)dst)[i] = (q0 & 255) | ((q1 & 255) << 8) | ((q2 & 255) << 16) | (q3 << 24);
    }
}

// quantize to bf16 integer levels (attention inputs)
__global__ __launch_bounds__(256) void quant_bf16_kernel(const float* __restrict__ src,
                                                         short* __restrict__ dst,
                                                         long long n4, long long npad4,
                                                         const float* __restrict__ am) {
    float s = scale_of(am);
    long long stride = (long long)gridDim.x * blockDim.x;
    for (long long i = (long long)blockIdx.x * blockDim.x + threadIdx.x; i < npad4; i += stride) {
        float4 v = make_float4(0.f, 0.f, 0.f, 0.f);
        if (i < n4) v = ((const float4*)src)[i];
        float qx = fminf(fmaxf(rintf(v.x / s), -127.f), 127.f);
        float qy = fminf(fmaxf(rintf(v.y / s), -127.f), 127.f);
        float qz = fminf(fmaxf(rintf(v.z / s), -127.f), 127.f);
        float qw = fminf(fmaxf(rintf(v.w / s), -127.f), 127.f);
        short4 o;
        o.x = bf16_of_small_int(qx);
        o.y = bf16_of_small_int(qy);
        o.z = bf16_of_small_int(qz);
        o.w = bf16_of_small_int(qw);
        ((short4*)dst)[i] = o;
    }
}

// transpose V levels: qkvq[b*197+m][2048+h*64+d] -> vtq[z][d][m] (stride KPAD)
__global__ __launch_bounds__(256) void vt_kernel(const short* __restrict__ qkvq,
                                                 short* __restrict__ vtq) {
    __shared__ short T[NSEQ * 65];
    int z = blockIdx.x, b = z >> 4, hh = z & 15;
    int tid = threadIdx.x;
    const short* vbase = qkvq + (size_t)b * NSEQ * QKVD + 2048 + hh * 64;
    for (int c = tid; c < NSEQ * 8; c += 256) {
        int m = c >> 3, piece = c & 7;
        bf16x8 v = *(const bf16x8*)&vbase[(size_t)m * QKVD + piece * 8];
        #pragma unroll
        for (int jj = 0; jj < 8; jj++) T[m * 65 + piece * 8 + jj] = v[jj];
    }
    __syncthreads();
    short* obase = vtq + (size_t)z * 64 * KPAD;
    for (int c = tid; c < 64 * (KPAD / 8); c += 256) {
        int d = c / (KPAD / 8), mc = c % (KPAD / 8);
        bf16x8 o;
        #pragma unroll
        for (int jj = 0; jj < 8; jj++) {
            int m = mc * 8 + jj;
            o[jj] = (m < NSEQ) ? T[m * 65 + d] : (short)0;
        }
        *(bf16x8*)&obase[(size_t)d * KPAD + mc * 8] = o;
    }
}

// wave-per-row softmax: fq(S row) -> softmax -> P levels (rint(p*255), bf16), pad to KPAD
__global__ __launch_bounds__(256) void softmax_kernel(const float* __restrict__ S,
                                                      short* __restrict__ pq,
                                                      const float* __restrict__ am) {
    int wave = threadIdx.x >> 6, lane = threadIdx.x & 63;
    long long row = (long long)blockIdx.x * 4 + wave;
    if (row >= (long long)NBH * NSEQ) return;
    int z = (int)(row / NSEQ), r = (int)(row % NSEQ);
    const float* src = S + (size_t)z * SSZ + (size_t)r * NSEQ;
    short* dst = pq + ((size_t)z * NSEQ + r) * KPAD;
    float s = scale_of(am);
    float v[4], mx = -3.0e38f;
    #pragma unroll
    for (int i = 0; i < 4; i++) {
        int c = lane + i * 64;
        v[i] = (c < NSEQ) ? fqv(src[c], s) : -3.0e38f;
        mx = fmaxf(mx, v[i]);
    }
    #pragma unroll
    for (int o = 32; o > 0; o >>= 1) mx = fmaxf(mx, __shfl_xor(mx, o));
    float e[4], sum = 0.f;
    #pragma unroll
    for (int i = 0; i < 4; i++) {
        int c = lane + i * 64;
        e[i] = (c < NSEQ) ? expf(v[i] - mx) : 0.f;
        sum += e[i];
    }
    #pragma unroll
    for (int o = 32; o > 0; o >>= 1) sum += __shfl_xor(sum, o);
    #pragma unroll
    for (int i = 0; i < 4; i++) {
        int c = lane + i * 64;
        if (c < KPAD) {
            float plvl = (c < NSEQ) ? rintf(e[i] / sum * 255.0f) : 0.f;
            dst[c] = bf16_of_small_int(plvl);
        }
    }
}

#define GLL(gp, lp) __builtin_amdgcn_global_load_lds( \
    (const __attribute__((address_space(1))) void*)(gp), \
    (__attribute__((address_space(3))) void*)(lp), 16, 0, 0)

// ---------- i8 MFMA GEMM, 4-wave 128x128 ----------
// 2-buffer, 2 barriers/K64-step, 4-slot XOR swizzle, LDS 32KB -> 4 blocks/CU.
template <int EPI>  // 0: scale+bias, 1: scale+bias+gelu
__global__ __launch_bounds__(256, 4) void mfma_gemm_kernel(
    const signed char* __restrict__ Aq, const signed char* __restrict__ Bq,
    const float* __restrict__ bias, float* __restrict__ C,
    int M, int N, int K, int NBX,
    const float* __restrict__ amA, const float* __restrict__ amB,
    float* __restrict__ amOut) {
    __shared__ __align__(16) signed char As[2][128 * 64];
    __shared__ __align__(16) signed char Bs[2][128 * 64];
    __shared__ float sred[4];
    const int tid = threadIdx.x;
    const int lane = tid & 63;
    const int wave = tid >> 6;
    const int wg = (blockIdx.x & 7) * ((int)gridDim.x >> 3) + ((int)blockIdx.x >> 3);
    const int n0 = (wg % NBX) * 128;
    const int m0 = (wg / NBX) * 128;
    const int wm = (wave >> 1) * 64;
    const int wn = (wave & 1) * 64;
    const float sAB = fmaxf(amA[0] / 127.0f, 1e-8f) * fmaxf(amB[0] / 127.0f, 1e-8f);

    i32x4 acc[4][4] = {};

    const signed char* gA[2];
    const signed char* gB[2];
    #pragma unroll
    for (int i = 0; i < 2; i++) {
        int s = tid + 256 * i;
        int row = s >> 2;
        int gsl = ((s & 3) ^ (row & 3)) * 16;
        gA[i] = Aq + (size_t)(m0 + row) * K + gsl;
        gB[i] = Bq + (size_t)(n0 + row) * K + gsl;
    }
    const int lr = lane & 15;
    const int klane = lane >> 4;
    int offA[4], offB[4];
    #pragma unroll
    for (int i = 0; i < 4; i++) {
        int ra = wm + i * 16 + lr;
        int rb = wn + i * 16 + lr;
        offA[i] = ra * 64 + ((klane ^ (ra & 3)) * 16);
        offB[i] = rb * 64 + ((klane ^ (rb & 3)) * 16);
    }

#define STAGE(buf, kk) do { \
    _Pragma("unroll") \
    for (int i = 0; i < 2; i++) { \
        GLL(gA[i] + (kk), &As[buf][wave * 1024 + i * 4096]); \
        GLL(gB[i] + (kk), &Bs[buf][wave * 1024 + i * 4096]); \
    } \
} while (0)

#define COMPUTE(buf) do { \
    i32x4 a[4], b[4]; \
    _Pragma("unroll") \
    for (int i = 0; i < 4; i++) { \
        a[i] = *(const i32x4*)&As[buf][offA[i]]; \
        b[i] = *(const i32x4*)&Bs[buf][offB[i]]; \
    } \
    _Pragma("unroll") \
    for (int i = 0; i < 4; i++) \
        _Pragma("unroll") \
        for (int j = 0; j < 4; j++) \
            acc[i][j] = __builtin_amdgcn_mfma_i32_16x16x64_i8(a[i], b[j], acc[i][j], 0, 0, 0); \
} while (0)

    STAGE(0, 0);
    __syncthreads();
    int k0 = 0;
    for (; k0 + 128 < K; k0 += 128) {
        STAGE(1, k0 + 64);
        COMPUTE(0);
        __syncthreads();
        STAGE(0, k0 + 128);
        COMPUTE(1);
        __syncthreads();
    }
    STAGE(1, k0 + 64);
    COMPUTE(0);
    __syncthreads();
    COMPUTE(1);
#undef STAGE
#undef COMPUTE

    const int cr = (lane >> 4) * 4;
    const int cc = lane & 15;
    float mloc = 0.f;
    #pragma unroll
    for (int i = 0; i < 4; i++) {
        #pragma unroll
        for (int j = 0; j < 4; j++) {
            int gn = n0 + wn + j * 16 + cc;
            float bv = bias[gn];
            #pragma unroll
            for (int r = 0; r < 4; r++) {
                int gm = m0 + wm + i * 16 + cr + r;
                if (gm >= M) continue;
                float v = (float)acc[i][j][r] * sAB + bv;
                if (EPI == 1) v = gelu_f(v);
                C[(size_t)gm * N + gn] = v;
                mloc = fmaxf(mloc, fabsf(v));
            }
        }
    }
    mloc = blockReduceMax(mloc, sred);
    if (tid == 0) atomicMaxF(amOut, mloc);
}

// ---------- i8 MFMA GEMM, 8-wave 256x128 (qkv, fc1) ----------
template <int EPI>
__global__ __launch_bounds__(512, 4) void mfma_gemm8_kernel(
    const signed char* __restrict__ Aq, const signed char* __restrict__ Bq,
    const float* __restrict__ bias, float* __restrict__ C,
    int M, int N, int K, int NBX,
    const float* __restrict__ amA, const float* __restrict__ amB,
    float* __restrict__ amOut) {
    __shared__ __align__(16) signed char As[2][256 * 64];
    __shared__ __align__(16) signed char Bs[2][128 * 64];
    __shared__ float sred[8];
    const int tid = threadIdx.x;
    const int lane = tid & 63;
    const int wave = tid >> 6;           // 0..7
    const int wg = (blockIdx.x & 7) * ((int)gridDim.x >> 3) + ((int)blockIdx.x >> 3);
    const int n0 = (wg % NBX) * 128;
    const int m0 = (wg / NBX) * 256;
    const int wm = (wave >> 1) * 64;     // 0,64,128,192
    const int wn = (wave & 1) * 64;      // 0,64
    const float sAB = fmaxf(amA[0] / 127.0f, 1e-8f) * fmaxf(amB[0] / 127.0f, 1e-8f);

    i32x4 acc[4][4] = {};

    const signed char* gA[2];
    #pragma unroll
    for (int i = 0; i < 2; i++) {
        int s = tid + 512 * i;
        int row = s >> 2;
        int gsl = ((s & 3) ^ (row & 3)) * 16;
        gA[i] = Aq + (size_t)(m0 + row) * K + gsl;
    }
    const signed char* gB;
    {
        int row = tid >> 2;
        int gsl = ((tid & 3) ^ (row & 3)) * 16;
        gB = Bq + (size_t)(n0 + row) * K + gsl;
    }
    const int lr = lane & 15;
    const int klane = lane >> 4;
    int offA[4], offB[4];
    #pragma unroll
    for (int i = 0; i < 4; i++) {
        int ra = wm + i * 16 + lr;
        int rb = wn + i * 16 + lr;
        offA[i] = ra * 64 + ((klane ^ (ra & 3)) * 16);
        offB[i] = rb * 64 + ((klane ^ (rb & 3)) * 16);
    }

#define STAGE(buf, kk) do { \
    GLL(gA[0] + (kk), &As[buf][wave * 1024]); \
    GLL(gA[1] + (kk), &As[buf][wave * 1024 + 8192]); \
    GLL(gB + (kk),    &Bs[buf][wave * 1024]); \
} while (0)

#define COMPUTE(buf) do { \
    i32x4 a[4], b[4]; \
    _Pragma("unroll") \
    for (int i = 0; i < 4; i++) { \
        a[i] = *(const i32x4*)&As[buf][offA[i]]; \
        b[i] = *(const i32x4*)&Bs[buf][offB[i]]; \
    } \
    _Pragma("unroll") \
    for (int i = 0; i < 4; i++) \
        _Pragma("unroll") \
        for (int j = 0; j < 4; j++) \
            acc[i][j] = __builtin_amdgcn_mfma_i32_16x16x64_i8(a[i], b[j], acc[i][j], 0, 0, 0); \
} while (0)

    STAGE(0, 0);
    __syncthreads();
    int k0 = 0;
    for (; k0 + 128 < K; k0 += 128) {
        STAGE(1, k0 + 64);
        COMPUTE(0);
        __syncthreads();
        STAGE(0, k0 + 128);
        COMPUTE(1);
        __syncthreads();
    }
    STAGE(1, k0 + 64);
    COMPUTE(0);
    __syncthreads();
    COMPUTE(1);
#undef STAGE
#undef COMPUTE

    const int cr = (lane >> 4) * 4;
    const int cc = lane & 15;
    float mloc = 0.f;
    #pragma unroll
    for (int i = 0; i < 4; i++) {
        #pragma unroll
        for (int j = 0; j < 4; j++) {
            int gn = n0 + wn + j * 16 + cc;
            float bv = bias[gn];
            #pragma unroll
            for (int r = 0; r < 4; r++) {
                int gm = m0 + wm + i * 16 + cr + r;
                if (gm >= M) continue;
                float v = (float)acc[i][j][r] * sAB + bv;
                if (EPI == 1) v = gelu_f(v);
                C[(size_t)gm * N + gn] = v;
                mloc = fmaxf(mloc, fabsf(v));
            }
        }
    }
    mloc = blockReduceMax8(mloc, sred);
    if (tid == 0) atomicMaxF(amOut, mloc);
}

// ---------- MFMA attention QK^T (bf16) ----------
__global__ __launch_bounds__(256, 2) void attn_qk_kernel(
    const short* __restrict__ qkvq, float* __restrict__ S,
    const float* __restrict__ amQ, float* __restrict__ amOut) {
    __shared__ __align__(16) short Qs[256 * 32];
    __shared__ __align__(16) short Ks[64 * 32];
    __shared__ float sred[4];
    const int tid = threadIdx.x, lane = tid & 63, wave = tid >> 6;
    const int z = blockIdx.z, b = z >> 4, hh = z & 15;
    const int n0 = blockIdx.x * 64;
    const short* qbase = qkvq + (size_t)b * NSEQ * QKVD + hh * 64;
    const short* kbase = qbase + 1024;
    const float s5 = fmaxf(amQ[0] / 127.0f, 1e-8f);
    const float sc = s5 * s5 * 0.125f;

    f32x4 acc[4][4] = {};
    const int piece = (tid & 3) * 8;
    const short* srcA[4];
    #pragma unroll
    for (int i = 0; i < 4; i++) {
        int row = i * 64 + (tid >> 2);
        srcA[i] = qbase + (size_t)min(row, NSEQ - 1) * QKVD + piece;
    }
    const short* srcB = kbase + (size_t)min(n0 + (tid >> 2), NSEQ - 1) * QKVD + piece;
    const int lr = lane & 15;
    const int koff = (lane >> 4) * 8;

    for (int k0 = 0; k0 < 64; k0 += 32) {
        __syncthreads();
        #pragma unroll
        for (int i = 0; i < 4; i++) GLL(srcA[i] + k0, Qs + i * 2048 + wave * 512);
        GLL(srcB + k0, Ks + wave * 512);
        __syncthreads();

        bf16x8 a[4], bfr[4];
        #pragma unroll
        for (int i = 0; i < 4; i++)
            a[i] = *(const bf16x8*)&Qs[(wave * 64 + i * 16 + lr) * 32 + koff];
        #pragma unroll
        for (int j = 0; j < 4; j++)
            bfr[j] = *(const bf16x8*)&Ks[(j * 16 + lr) * 32 + koff];
        #pragma unroll
        for (int i = 0; i < 4; i++)
            #pragma unroll
            for (int j = 0; j < 4; j++)
                acc[i][j] = __builtin_amdgcn_mfma_f32_16x16x32_bf16(a[i], bfr[j], acc[i][j], 0, 0, 0);
    }

    const int cr = (lane >> 4) * 4;
    const int cc = lane & 15;
    float* sbase = S + (size_t)z * SSZ;
    float mloc = 0.f;
    #pragma unroll
    for (int i = 0; i < 4; i++) {
        #pragma unroll
        for (int j = 0; j < 4; j++) {
            int gn = n0 + j * 16 + cc;
            #pragma unroll
            for (int r = 0; r < 4; r++) {
                int gm = wave * 64 + i * 16 + cr + r;
                if (gm < NSEQ && gn < NSEQ) {
                    float v = acc[i][j][r] * sc;
                    sbase[(size_t)gm * NSEQ + gn] = v;
                    mloc = fmaxf(mloc, fabsf(v));
                }
            }
        }
    }
    mloc = blockReduceMax(mloc, sred);
    if (tid == 0) atomicMaxF(amOut, mloc);
}

// ---------- MFMA attention PV (bf16) ----------
__global__ __launch_bounds__(256, 2) void attn_pv_kernel(
    const short* __restrict__ pq, const short* __restrict__ vtq,
    float* __restrict__ xa,
    const float* __restrict__ amV, float* __restrict__ amOut) {
    __shared__ __align__(16) short Ps[256 * 32];
    __shared__ __align__(16) short Vs[64 * 32];
    __shared__ float sred[4];
    const int tid = threadIdx.x, lane = tid & 63, wave = tid >> 6;
    const int z = blockIdx.z, b = z >> 4, hh = z & 15;
    const short* pbase = pq + (size_t)z * NSEQ * KPAD;
    const short* vbase = vtq + (size_t)z * 64 * KPAD;
    const float sc = fmaxf(amV[0] / 127.0f, 1e-8f) * (1.0f / 255.0f);

    f32x4 acc[4][4] = {};
    const int piece = (tid & 3) * 8;
    const short* srcA[4];
    #pragma unroll
    for (int i = 0; i < 4; i++) {
        int row = i * 64 + (tid >> 2);
        srcA[i] = pbase + (size_t)min(row, NSEQ - 1) * KPAD + piece;
    }
    const short* srcB = vbase + (size_t)(tid >> 2) * KPAD + piece;
    const int lr = lane & 15;
    const int koff = (lane >> 4) * 8;

    for (int k0 = 0; k0 < KPAD; k0 += 32) {
        __syncthreads();
        #pragma unroll
        for (int i = 0; i < 4; i++) GLL(srcA[i] + k0, Ps + i * 2048 + wave * 512);
        GLL(srcB + k0, Vs + wave * 512);
        __syncthreads();

        bf16x8 a[4], bfr[4];
        #pragma unroll
        for (int i = 0; i < 4; i++)
            a[i] = *(const bf16x8*)&Ps[(wave * 64 + i * 16 + lr) * 32 + koff];
        #pragma unroll
        for (int j = 0; j < 4; j++)
            bfr[j] = *(const bf16x8*)&Vs[(j * 16 + lr) * 32 + koff];
        #pragma unroll
        for (int i = 0; i < 4; i++)
            #pragma unroll
            for (int j = 0; j < 4; j++)
                acc[i][j] = __builtin_amdgcn_mfma_f32_16x16x32_bf16(a[i], bfr[j], acc[i][j], 0, 0, 0);
    }

    const int cr = (lane >> 4) * 4;
    const int cc = lane & 15;
    float mloc = 0.f;
    #pragma unroll
    for (int i = 0; i < 4; i++) {
        #pragma unroll
        for (int j = 0; j < 4; j++) {
            int gn = j * 16 + cc;
            #pragma unroll
            for (int r = 0; r < 4; r++) {
                int gm = wave * 64 + i * 16 + cr + r;
                if (gm < NSEQ) {
                    float v = acc[i][j][r] * sc;
                    xa[((size_t)b * NSEQ + gm) * CDIM + hh * 64 + gn] = v;
                    mloc = fmaxf(mloc, fabsf(v));
                }
            }
        }
    }
    mloc = blockReduceMax(mloc, sred);
    if (tid == 0) atomicMaxF(amOut, mloc);
}

// ---------- launcher ----------
extern "C" void kernel_launch(void* const* d_in, const int* in_sizes, int n_in,
                              void* d_out, int out_size, void* d_ws, size_t ws_size,
                              hipStream_t stream) {
    (void)in_sizes; (void)n_in; (void)out_size; (void)ws_size;
    const float* x      = (const float*)d_in[0];
    const float* g1     = (const float*)d_in[1];
    const float* b1     = (const float*)d_in[2];
    const float* w_qkv  = (const float*)d_in[3];
    const float* b_qkv  = (const float*)d_in[4];
    const float* w_proj = (const float*)d_in[5];
    const float* b_proj = (const float*)d_in[6];
    const float* g2     = (const float*)d_in[7];
    const float* b2     = (const float*)d_in[8];
    const float* w_fc1  = (const float*)d_in[9];
    const float* b_fc1  = (const float*)d_in[10];
    const float* w_fc2  = (const float*)d_in[11];
    const float* b_fc2  = (const float*)d_in[12];
    float* out = (float*)d_out;
    float* ws  = (float*)d_ws;

    // amax slots: 0 wqkv 1 wproj 2 wfc1 3 wfc2 4 xn1 5 qkvout 6 attn 7 xa
    //             8 projout 9 x1 10 xn2 11 gelu(=h1) 13 fc2out 14 final
    float* am            = ws;
    signed char* wq_qkv  = (signed char*)(ws + 64);
    signed char* wq_proj = wq_qkv + (size_t)QKVD * CDIM;
    signed char* wq_fc1  = wq_proj + (size_t)CDIM * CDIM;
    signed char* wq_fc2  = wq_fc1 + (size_t)FFD * CDIM;
    signed char* xnq     = wq_fc2 + (size_t)CDIM * FFD;       // MPAD*CDIM i8
    float* y             = (float*)(xnq + (size_t)MPAD * CDIM);
    short* qkvq          = (short*)(y + (size_t)ROWS * CDIM); // ROWS*QKVD bf16
    float* R             = (float*)(qkvq + (size_t)ROWS * QKVD);
    float* qkvF          = R;                                 // ROWS*QKVD f32
    float* S             = R;                                 // NBH*SSZ f32
    short* pq            = (short*)(S + (size_t)NBH * SSZ);   // NBH*NSEQ*KPAD bf16
    short* vtq           = (short*)y;                         // aliases y
    float* h             = (float*)qkvq;                      // ROWS*FFD f32 (attn dead)
    signed char* hq      = (signed char*)(h + (size_t)ROWS * FFD); // MPAD*FFD i8
    float* xa = out;

    hipMemsetAsync(am, 0, 64 * sizeof(float), stream);
    hipMemsetAsync(xnq + (size_t)ROWS * CDIM, 0, (size_t)(MPAD - ROWS) * CDIM, stream);

    // weight prep: segment-parallel, static trip counts (fixes r9's 98 µs anomaly)
    wprep_absmax_kernel<<<3072, 256, 0, stream>>>(w_qkv, w_proj, w_fc1, w_fc2, am);
    wprep_quant_kernel<<<3072, 256, 0, stream>>>(
        w_qkv, wq_qkv, w_proj, wq_proj, w_fc1, wq_fc1, w_fc2, wq_fc2, am);

    // LN1: amax pass + recompute-quant pass (no f32 intermediate)
    ln_kernel<0><<<ROWS, 256, 0, stream>>>(x, g1, b1, nullptr, nullptr, nullptr, am + 4);
    ln_kernel<1><<<ROWS, 256, 0, stream>>>(x, g1, b1, xnq, nullptr, am + 4, nullptr);

    // qkv (8-wave 256x128, grid 25x24 = 600)
    mfma_gemm8_kernel<0><<<600, 512, 0, stream>>>(
        xnq, wq_qkv, b_qkv, qkvF, ROWS, QKVD, CDIM, QKVD / 128, am + 4, am + 0, am + 5);
    quant_bf16_kernel<<<2048, 256, 0, stream>>>(qkvF, qkvq,
        (long long)ROWS * QKVD / 4, (long long)ROWS * QKVD / 4, am + 5);
    vt_kernel<<<NBH, 256, 0, stream>>>(qkvq, vtq);

    // S = Q @ K^T * 0.125, fused amax -> am6
    attn_qk_kernel<<<dim3(4, 1, NBH), 256, 0, stream>>>(qkvq, S, am + 5, am + 6);
    softmax_kernel<<<(NBH * NSEQ + 3) / 4, 256, 0, stream>>>(S, pq, am + 6);
    attn_pv_kernel<<<dim3(1, 1, NBH), 256, 0, stream>>>(pq, vtq, xa, am + 5, am + 7);

    // proj (4-wave 128x128, grid 400)
    quant_i8_kernel<<<2048, 256, 0, stream>>>(xa, xnq,
        (long long)ROWS * CDIM / 4, (long long)MPAD * CDIM / 4, am + 7);
    mfma_gemm_kernel<0><<<400, 256, 0, stream>>>(
        xnq, wq_proj, b_proj, y, ROWS, CDIM, CDIM, CDIM / 128, am + 7, am + 1, am + 8);

    // residual 1: y = x + fq8(y); am9 = max|y|
    addfq_kernel<<<2048, 256, 0, stream>>>(x, nullptr, y, (long long)ROWS * CDIM / 4,
                                           am + 8, am + 9);

    // LN2 (fused fq9 on load): amax + recompute-quant
    ln_kernel<0><<<ROWS, 256, 0, stream>>>(y, g2, b2, nullptr, am + 9, nullptr, am + 10);
    ln_kernel<1><<<ROWS, 256, 0, stream>>>(y, g2, b2, xnq, am + 9, am + 10, nullptr);

    // fc1 (8-wave 256x128, grid 25x32 = 800; gelu epilogue, amax -> am11)
    mfma_gemm8_kernel<1><<<800, 512, 0, stream>>>(
        xnq, wq_fc1, b_fc1, h, ROWS, FFD, CDIM, FFD / 128, am + 10, am + 2, am + 11);
    // h1 = fq(gelu); fq∘fq identity => quantize directly with s(am11)
    quant_i8_kernel<<<4096, 256, 0, stream>>>(h, hq,
        (long long)ROWS * FFD / 4, (long long)MPAD * FFD / 4, am + 11);

    // fc2 (4-wave 128x128, grid 400)
    mfma_gemm_kernel<0><<<400, 256, 0, stream>>>(
        hq, wq_fc2, b_fc2, out, ROWS, CDIM, FFD, CDIM / 128, am + 11, am + 3, am + 13);

    // residual 2: out = fq9(y) + fq13(out); am14; final out = fq14(out)
    addfq_kernel<<<2048, 256, 0, stream>>>(y, am + 9, out, (long long)ROWS * CDIM / 4,
                                           am + 13, am + 14);
    fq_inplace_kernel<<<2048, 256, 0, stream>>>(out, (long long)ROWS * CDIM / 4, am + 14, nullptr);
}